// Round 1
// baseline (2508.519 us; speedup 1.0000x reference)
//
#include <hip/hip_runtime.h>

#define NND 50000
#define NE  800000
#define NET 850000   // NE + NND self-loops
#define NG  2048
#define HC  128      // HEADS*HID

__device__ __forceinline__ float frelu(float v){ return v > 0.f ? v : 0.f; }

// ---------------- mean of edge_features over E rows -> acc8[8] (sum) -------------
__global__ void k_mean(const float* __restrict__ ef, float* __restrict__ acc8){
    int i0 = blockIdx.x * blockDim.x + threadIdx.x;
    int stride = gridDim.x * blockDim.x;        // multiple of 8 (1024*256)
    float s = 0.f;
    for (int i = i0; i < NE * 8; i += stride) s += ef[i];
    atomicAdd(&acc8[i0 & 7], s);
}

// ---------------- M[3][8][4] and self-loop al_e constants sc[3][4] ---------------
__global__ void k_prep(const float* __restrict__ acc8,
                       const float* __restrict__ We1, const float* __restrict__ ae1,
                       const float* __restrict__ We2, const float* __restrict__ ae2,
                       const float* __restrict__ We3, const float* __restrict__ ae3,
                       float* __restrict__ M, float* __restrict__ sc){
    __shared__ float me[8];
    __shared__ float Ms[96];
    int t = threadIdx.x;
    if (t < 8) me[t] = acc8[t] * (1.0f / NE);
    if (t < 96){
        int l = t >> 5, f = (t >> 2) & 7, h = t & 3;
        const float* We = (l == 0) ? We1 : ((l == 1) ? We2 : We3);
        const float* ae = (l == 0) ? ae1 : ((l == 1) ? ae2 : ae3);
        float s = 0.f;
        for (int c = 0; c < 32; c++) s += We[f * 128 + h * 32 + c] * ae[h * 32 + c];
        M[t] = s; Ms[t] = s;
    }
    __syncthreads();
    if (t < 12){
        int l = t >> 2, h = t & 3;
        float s = 0.f;
        for (int f = 0; f < 8; f++) s += me[f] * Ms[l * 32 + f * 4 + h];
        sc[t] = s;
    }
}

// ------------- h = x @ W  (+ attention logits al_s, al_d) -----------------------
// block = 128 threads (one per output col), 4 rows per block (register tiling)
__global__ __launch_bounds__(128) void k_gemm(
        const float* __restrict__ x, const float* __restrict__ W,
        const float* __restrict__ asrc, const float* __restrict__ adst,
        float* __restrict__ h, float* __restrict__ als, float* __restrict__ ald,
        int Fin){
    __shared__ float xs[4 * 128];
    int tid = threadIdx.x;
    int r0 = blockIdx.x * 4;
    for (int i = tid; i < 4 * Fin; i += 128) xs[i] = x[r0 * Fin + i];
    __syncthreads();
    int col = tid;
    float wa_s = asrc[col], wa_d = adst[col];
    float a0 = 0.f, a1 = 0.f, a2 = 0.f, a3 = 0.f;
    for (int k = 0; k < Fin; k++){
        float wv = W[k * 128 + col];
        a0 += xs[k] * wv;
        a1 += xs[Fin + k] * wv;
        a2 += xs[2 * Fin + k] * wv;
        a3 += xs[3 * Fin + k] * wv;
    }
    int head = tid >> 5;
    bool lane0 = ((tid & 31) == 0);
    float accs[4] = {a0, a1, a2, a3};
    for (int r = 0; r < 4; r++){
        float v = accs[r];
        h[(r0 + r) * 128 + col] = v;
        float sv = v * wa_s, dv = v * wa_d;
        for (int off = 16; off > 0; off >>= 1){
            sv += __shfl_down(sv, off, 32);
            dv += __shfl_down(dv, off, 32);
        }
        if (lane0){
            als[(r0 + r) * 4 + head] = sv;
            ald[(r0 + r) * 4 + head] = dv;
        }
    }
}

// ------------- al_e[e,h] = ef[e,:] @ M  for real edges --------------------------
__global__ void k_ale(const float* __restrict__ ef, const float* __restrict__ M,
                      float* __restrict__ ale){
    int e = blockIdx.x * blockDim.x + threadIdx.x;
    if (e >= NE) return;
    const float4* efp = (const float4*)ef;
    float4 p = efp[e * 2], q = efp[e * 2 + 1];
    float4 o;
    float* op = &o.x;
    #pragma unroll
    for (int h = 0; h < 4; h++){
        op[h] = p.x * M[0 + h]  + p.y * M[4 + h]  + p.z * M[8 + h]  + p.w * M[12 + h]
              + q.x * M[16 + h] + q.y * M[20 + h] + q.z * M[24 + h] + q.w * M[28 + h];
    }
    ((float4*)ale)[e] = o;
}

// ------------- edge scatter: acc[dst,:] += w * h[src,:] ; den[dst,h] += w -------
__global__ void k_edge(const int* __restrict__ ei, const float* __restrict__ ale,
                       const float* __restrict__ sc4,
                       const float* __restrict__ als, const float* __restrict__ ald,
                       const float* __restrict__ h,
                       float* __restrict__ acc, float* __restrict__ den){
    int gtid = blockIdx.x * blockDim.x + threadIdx.x;
    int e = gtid >> 7;
    if (e >= NET) return;
    int c = gtid & 127, head = c >> 5;
    int s, d; float ae;
    if (e < NE){ s = ei[e]; d = ei[NE + e]; ae = ale[e * 4 + head]; }
    else       { s = e - NE; d = s;         ae = sc4[head]; }
    float a = als[s * 4 + head] + ald[d * 4 + head] + ae;
    a = a > 0.f ? a : 0.2f * a;            // leaky_relu(0.2)
    float w = __expf(a);                   // no max-subtraction needed (values O(1))
    atomicAdd(&acc[d * 128 + c], w * h[s * 128 + c]);
    if ((c & 31) == 0) atomicAdd(&den[d * 4 + head], w);
}

// ------------- out = relu(acc/den + b), in place --------------------------------
__global__ void k_norm(float* __restrict__ acc, const float* __restrict__ den,
                       const float* __restrict__ b){
    int i = blockIdx.x * blockDim.x + threadIdx.x;
    if (i >= NND * 128) return;
    int n = i >> 7, c = i & 127;
    float v = acc[i] / (den[n * 4 + (c >> 5)] + 1e-16f) + b[c];
    acc[i] = frelu(v);
}

// ------------- global add pool --------------------------------------------------
__global__ void k_pool(const float* __restrict__ y, const int* __restrict__ batch,
                       float* __restrict__ g){
    int i = blockIdx.x * blockDim.x + threadIdx.x;
    if (i >= NND * 128) return;
    int n = i >> 7, c = i & 127;
    atomicAdd(&g[batch[n] * 128 + c], y[i]);
}

// ------------- MLP head: 128->32->32->1, relu everywhere ------------------------
__global__ void k_mlp(const float* __restrict__ g,
                      const float* __restrict__ lw1, const float* __restrict__ lb1,
                      const float* __restrict__ lw2, const float* __restrict__ lb2,
                      const float* __restrict__ lw3, const float* __restrict__ lb3,
                      float* __restrict__ out){
    __shared__ float t1[4][32];
    __shared__ float t2[4][32];
    int tid = threadIdx.x, sub = tid >> 5, j = tid & 31;
    int gi = blockIdx.x * 4 + sub;
    const float* gr = g + gi * 128;
    float s = lb1[j];
    for (int c = 0; c < 128; c++) s += gr[c] * lw1[c * 32 + j];
    t1[sub][j] = frelu(s);
    __syncthreads();
    float s2 = lb2[j];
    for (int k = 0; k < 32; k++) s2 += t1[sub][k] * lw2[k * 32 + j];
    t2[sub][j] = frelu(s2);
    __syncthreads();
    if (j == 0){
        float o = lb3[0];
        for (int k = 0; k < 32; k++) o += t2[sub][k] * lw3[k];
        out[gi] = frelu(o);
    }
}

extern "C" void kernel_launch(void* const* d_in, const int* in_sizes, int n_in,
                              void* d_out, int out_size, void* d_ws, size_t ws_size,
                              hipStream_t stream) {
    const float* x     = (const float*)d_in[0];
    const int*   ei    = (const int*)  d_in[1];
    const float* ef    = (const float*)d_in[2];
    const int*   batch = (const int*)  d_in[3];
    const float* W[3]   = {(const float*)d_in[4],  (const float*)d_in[10], (const float*)d_in[16]};
    const float* as_[3] = {(const float*)d_in[5],  (const float*)d_in[11], (const float*)d_in[17]};
    const float* ad_[3] = {(const float*)d_in[6],  (const float*)d_in[12], (const float*)d_in[18]};
    const float* We[3]  = {(const float*)d_in[7],  (const float*)d_in[13], (const float*)d_in[19]};
    const float* ae[3]  = {(const float*)d_in[8],  (const float*)d_in[14], (const float*)d_in[20]};
    const float* b_[3]  = {(const float*)d_in[9],  (const float*)d_in[15], (const float*)d_in[21]};
    const float* lw1 = (const float*)d_in[22]; const float* lb1 = (const float*)d_in[23];
    const float* lw2 = (const float*)d_in[24]; const float* lb2 = (const float*)d_in[25];
    const float* lw3 = (const float*)d_in[26]; const float* lb3 = (const float*)d_in[27];

    float* ws   = (float*)d_ws;
    float* A    = ws;                 // h buffer       [NND*128]
    float* B    = A    + 6400000;     // acc / y buffer [NND*128]
    float* als  = B    + 6400000;     // [NND*4]
    float* ald  = als  + 200000;      // [NND*4]
    float* den  = ald  + 200000;      // [NND*4]
    float* ale  = den  + 200000;      // [NE*4]
    float* g    = ale  + 3200000;     // [NG*128]
    float* acc8 = g    + 262144;      // [8]
    float* M    = acc8 + 8;           // [3*8*4]
    float* sc   = M    + 96;          // [3*4]

    hipMemsetAsync(acc8, 0, 8 * sizeof(float), stream);
    k_mean<<<1024, 256, 0, stream>>>(ef, acc8);
    k_prep<<<1, 128, 0, stream>>>(acc8, We[0], ae[0], We[1], ae[1], We[2], ae[2], M, sc);

    const float* xin = x;
    for (int l = 0; l < 3; l++){
        int Fin = (l == 0) ? 30 : 128;
        k_gemm<<<NND / 4, 128, 0, stream>>>(xin, W[l], as_[l], ad_[l], A, als, ald, Fin);
        k_ale<<<(NE + 255) / 256, 256, 0, stream>>>(ef, M + l * 32, ale);
        hipMemsetAsync(B, 0, 6400000 * sizeof(float), stream);
        hipMemsetAsync(den, 0, 200000 * sizeof(float), stream);
        k_edge<<<(NET * 128) / 256, 256, 0, stream>>>(ei, ale, sc + l * 4, als, ald, A, B, den);
        k_norm<<<(NND * 128) / 256, 256, 0, stream>>>(B, den, b_[l]);
        xin = B;
    }

    hipMemsetAsync(g, 0, NG * 128 * sizeof(float), stream);
    k_pool<<<(NND * 128) / 256, 256, 0, stream>>>(B, batch, g);
    k_mlp<<<NG / 4, 128, 0, stream>>>(g, lw1, lb1, lw2, lb2, lw3, lb3, (float*)d_out);
}

// Round 2
// 1309.806 us; speedup vs baseline: 1.9152x; 1.9152x over previous
//
#include <hip/hip_runtime.h>

#define NND 50000
#define NE  800000
#define NET 850000   // NE + NND self-loops
#define NG  2048

__device__ __forceinline__ float frelu(float v){ return v > 0.f ? v : 0.f; }

// ---------------- mean of edge_features: block-reduce, 8 atomics/block ----------
__global__ __launch_bounds__(256) void k_mean(const float* __restrict__ ef,
                                              float* __restrict__ acc8){
    __shared__ float red[256];
    int tid = threadIdx.x;
    int i0 = blockIdx.x * 256 + tid;
    int stride = gridDim.x * 256;          // multiple of 8
    float s = 0.f;
    for (int i = i0; i < NE * 8; i += stride) s += ef[i];
    red[tid] = s;
    __syncthreads();
    for (int off = 128; off >= 8; off >>= 1){   // off always multiple of 8 -> same column
        if (tid < off) red[tid] += red[tid + off];
        __syncthreads();
    }
    if (tid < 8) atomicAdd(&acc8[tid], red[tid]);
}

// ---------------- M[3][8][4] and self-loop al_e constants sc[3][4] ---------------
__global__ void k_prep(const float* __restrict__ acc8,
                       const float* __restrict__ We1, const float* __restrict__ ae1,
                       const float* __restrict__ We2, const float* __restrict__ ae2,
                       const float* __restrict__ We3, const float* __restrict__ ae3,
                       float* __restrict__ M, float* __restrict__ sc){
    __shared__ float me[8];
    __shared__ float Ms[96];
    int t = threadIdx.x;
    if (t < 8) me[t] = acc8[t] * (1.0f / NE);
    if (t < 96){
        int l = t >> 5, f = (t >> 2) & 7, h = t & 3;
        const float* We = (l == 0) ? We1 : ((l == 1) ? We2 : We3);
        const float* ae = (l == 0) ? ae1 : ((l == 1) ? ae2 : ae3);
        float s = 0.f;
        for (int c = 0; c < 32; c++) s += We[f * 128 + h * 32 + c] * ae[h * 32 + c];
        M[t] = s; Ms[t] = s;
    }
    __syncthreads();
    if (t < 12){
        int l = t >> 2, h = t & 3;
        float s = 0.f;
        for (int f = 0; f < 8; f++) s += me[f] * Ms[l * 32 + f * 4 + h];
        sc[t] = s;
    }
}

// ------------- h = x @ W  (+ attention logits al_s, al_d) -----------------------
__global__ __launch_bounds__(128) void k_gemm(
        const float* __restrict__ x, const float* __restrict__ W,
        const float* __restrict__ asrc, const float* __restrict__ adst,
        float* __restrict__ h, float* __restrict__ als, float* __restrict__ ald,
        int Fin){
    __shared__ float xs[4 * 128];
    int tid = threadIdx.x;
    int r0 = blockIdx.x * 4;
    for (int i = tid; i < 4 * Fin; i += 128) xs[i] = x[r0 * Fin + i];
    __syncthreads();
    int col = tid;
    float wa_s = asrc[col], wa_d = adst[col];
    float a0 = 0.f, a1 = 0.f, a2 = 0.f, a3 = 0.f;
    for (int k = 0; k < Fin; k++){
        float wv = W[k * 128 + col];
        a0 += xs[k] * wv;
        a1 += xs[Fin + k] * wv;
        a2 += xs[2 * Fin + k] * wv;
        a3 += xs[3 * Fin + k] * wv;
    }
    int head = tid >> 5;
    bool lane0 = ((tid & 31) == 0);
    float accs[4] = {a0, a1, a2, a3};
    for (int r = 0; r < 4; r++){
        float v = accs[r];
        h[(r0 + r) * 128 + col] = v;
        float sv = v * wa_s, dv = v * wa_d;
        for (int off = 16; off > 0; off >>= 1){
            sv += __shfl_down(sv, off, 32);
            dv += __shfl_down(dv, off, 32);
        }
        if (lane0){
            als[(r0 + r) * 4 + head] = sv;
            ald[(r0 + r) * 4 + head] = dv;
        }
    }
}

// ---------------- CSR build: histogram of dst -----------------------------------
__global__ void k_hist(const int* __restrict__ ei, int* __restrict__ cnt){
    int e = blockIdx.x * 256 + threadIdx.x;
    if (e >= NET) return;
    int d = (e < NE) ? ei[NE + e] : (e - NE);
    atomicAdd(&cnt[d], 1);
}

// ---------------- CSR build: exclusive scan (single block) ----------------------
__global__ __launch_bounds__(1024) void k_scan(const int* __restrict__ cnt,
                                               int* __restrict__ rs){
    __shared__ int ls[1024];
    int t = threadIdx.x;
    const int CH = (NND + 1023) / 1024;     // 49
    int base = t * CH;
    int s = 0;
    for (int i = 0; i < CH; i++){
        int idx = base + i;
        if (idx < NND) s += cnt[idx];
    }
    ls[t] = s;
    __syncthreads();
    for (int off = 1; off < 1024; off <<= 1){
        int v = (t >= off) ? ls[t - off] : 0;
        __syncthreads();
        ls[t] += v;
        __syncthreads();
    }
    int run = (t == 0) ? 0 : ls[t - 1];     // exclusive prefix of this chunk
    for (int i = 0; i < CH; i++){
        int idx = base + i;
        if (idx <= NND) rs[idx] = run;
        if (idx < NND)  run += cnt[idx];
    }
}

// ---------------- CSR build: scatter (s, e) into slots --------------------------
__global__ void k_scatter(const int* __restrict__ ei, const int* __restrict__ rs,
                          int* __restrict__ cnt2, int2* __restrict__ se){
    int e = blockIdx.x * 256 + threadIdx.x;
    if (e >= NET) return;
    int s, d;
    if (e < NE){ s = ei[e]; d = ei[NE + e]; } else { s = e - NE; d = s; }
    int pos = atomicAdd(&cnt2[d], 1);
    se[rs[d] + pos] = make_int2(s, e);
}

// ---------------- gather aggregation (fused softmax-norm + bias + relu) ---------
// block = one destination node, 128 threads = channels
__global__ __launch_bounds__(128) void k_gather(
        const int2* __restrict__ se, const int* __restrict__ rs,
        const float* __restrict__ als, const float* __restrict__ ald,
        const float* __restrict__ ef, const float* __restrict__ M,
        const float* __restrict__ sc4, const float* __restrict__ h,
        const float* __restrict__ b, float* __restrict__ out){
    int d = blockIdx.x;
    int c = threadIdx.x;
    int head = c >> 5;
    int start = rs[d], end = rs[d + 1];
    float aldv = ald[d * 4 + head];
    bool wlane = ((c & 31) == 0);
    int src = c & 32;                        // source lane within the 64-wide wave
    float accv = 0.f, accw = 0.f;
    for (int i = start; i < end; i++){
        int2 p = se[i];
        float w = 0.f;
        if (wlane){
            float aeh;
            if (p.y < NE){
                const float4* efp = (const float4*)ef;
                float4 u = efp[p.y * 2], v = efp[p.y * 2 + 1];
                aeh = u.x * M[0 + head]  + u.y * M[4 + head]
                    + u.z * M[8 + head]  + u.w * M[12 + head]
                    + v.x * M[16 + head] + v.y * M[20 + head]
                    + v.z * M[24 + head] + v.w * M[28 + head];
            } else {
                aeh = sc4[head];
            }
            float a = als[p.x * 4 + head] + aldv + aeh;
            a = a > 0.f ? a : 0.2f * a;      // leaky_relu(0.2)
            w = __expf(a);                   // values O(1): no max-subtraction needed
        }
        w = __shfl(w, src, 64);
        accv += w * h[p.x * 128 + c];
        accw += w;
    }
    out[d * 128 + c] = frelu(accv / (accw + 1e-16f) + b[c]);
}

// ---------------- global add pool: run-length compress sorted batch -------------
__global__ __launch_bounds__(128) void k_pool(const float* __restrict__ y,
                                              const int* __restrict__ batch,
                                              float* __restrict__ g){
    int c = threadIdx.x;                     // channel
    int n0 = blockIdx.x * 32;                // node chunk
    if (n0 >= NND) return;
    int cur = batch[n0];
    float s = 0.f;
    for (int k = 0; k < 32; k++){
        int n = n0 + k;
        if (n >= NND) break;
        int bg = batch[n];
        if (bg != cur){
            atomicAdd(&g[cur * 128 + c], s);
            s = 0.f; cur = bg;
        }
        s += y[n * 128 + c];
    }
    atomicAdd(&g[cur * 128 + c], s);
}

// ---------------- MLP head: 128->32->32->1 --------------------------------------
__global__ void k_mlp(const float* __restrict__ g,
                      const float* __restrict__ lw1, const float* __restrict__ lb1,
                      const float* __restrict__ lw2, const float* __restrict__ lb2,
                      const float* __restrict__ lw3, const float* __restrict__ lb3,
                      float* __restrict__ out){
    __shared__ float t1[4][32];
    __shared__ float t2[4][32];
    int tid = threadIdx.x, sub = tid >> 5, j = tid & 31;
    int gi = blockIdx.x * 4 + sub;
    const float* gr = g + gi * 128;
    float s = lb1[j];
    for (int c = 0; c < 128; c++) s += gr[c] * lw1[c * 32 + j];
    t1[sub][j] = frelu(s);
    __syncthreads();
    float s2 = lb2[j];
    for (int k = 0; k < 32; k++) s2 += t1[sub][k] * lw2[k * 32 + j];
    t2[sub][j] = frelu(s2);
    __syncthreads();
    if (j == 0){
        float o = lb3[0];
        for (int k = 0; k < 32; k++) o += t2[sub][k] * lw3[k];
        out[gi] = frelu(o);
    }
}

extern "C" void kernel_launch(void* const* d_in, const int* in_sizes, int n_in,
                              void* d_out, int out_size, void* d_ws, size_t ws_size,
                              hipStream_t stream) {
    const float* x     = (const float*)d_in[0];
    const int*   ei    = (const int*)  d_in[1];
    const float* ef    = (const float*)d_in[2];
    const int*   batch = (const int*)  d_in[3];
    const float* W[3]   = {(const float*)d_in[4],  (const float*)d_in[10], (const float*)d_in[16]};
    const float* as_[3] = {(const float*)d_in[5],  (const float*)d_in[11], (const float*)d_in[17]};
    const float* ad_[3] = {(const float*)d_in[6],  (const float*)d_in[12], (const float*)d_in[18]};
    const float* We[3]  = {(const float*)d_in[7],  (const float*)d_in[13], (const float*)d_in[19]};
    const float* ae[3]  = {(const float*)d_in[8],  (const float*)d_in[14], (const float*)d_in[20]};
    const float* b_[3]  = {(const float*)d_in[9],  (const float*)d_in[15], (const float*)d_in[21]};
    const float* lw1 = (const float*)d_in[22]; const float* lb1 = (const float*)d_in[23];
    const float* lw2 = (const float*)d_in[24]; const float* lb2 = (const float*)d_in[25];
    const float* lw3 = (const float*)d_in[26]; const float* lb3 = (const float*)d_in[27];

    float* ws   = (float*)d_ws;
    float* A    = ws;                          // h buffer        [NND*128]
    float* B    = A    + 6400000;              // layer output    [NND*128]
    float* als  = B    + 6400000;              // [NND*4]
    float* ald  = als  + 200000;               // [NND*4]
    int2*  se   = (int2*)(ald + 200000);       // [NET] (src, edge-id) — 1.7M units
    int*   rs   = (int*)(se + NET);            // row_start [NND+1]
    int*   cnt  = rs + NND + 2;                // [NND] (keep 8B alignment slack)
    int*   cnt2 = cnt + NND;                   // [NND]
    float* g    = (float*)(cnt2 + NND);        // [NG*128]
    float* acc8 = g + NG * 128;                // [8]
    float* M    = acc8 + 8;                    // [3*8*4]
    float* sc   = M + 96;                      // [3*4]

    hipMemsetAsync(acc8, 0, 8 * sizeof(float), stream);
    hipMemsetAsync(cnt,  0, NND * sizeof(int), stream);
    hipMemsetAsync(cnt2, 0, NND * sizeof(int), stream);
    hipMemsetAsync(g,    0, NG * 128 * sizeof(float), stream);

    k_mean<<<256, 256, 0, stream>>>(ef, acc8);
    k_prep<<<1, 128, 0, stream>>>(acc8, We[0], ae[0], We[1], ae[1], We[2], ae[2], M, sc);

    // CSR by destination (edge_index is call-invariant: build once per call)
    k_hist<<<(NET + 255) / 256, 256, 0, stream>>>(ei, cnt);
    k_scan<<<1, 1024, 0, stream>>>(cnt, rs);
    k_scatter<<<(NET + 255) / 256, 256, 0, stream>>>(ei, rs, cnt2, se);

    const float* xin = x;
    float* hbuf = A;
    float* obuf = B;
    for (int l = 0; l < 3; l++){
        int Fin = (l == 0) ? 30 : 128;
        k_gemm<<<NND / 4, 128, 0, stream>>>(xin, W[l], as_[l], ad_[l], hbuf, als, ald, Fin);
        k_gather<<<NND, 128, 0, stream>>>(se, rs, als, ald, ef, M + l * 32, sc + l * 4,
                                          hbuf, b_[l], obuf);
        xin = obuf;
        float* t = hbuf; hbuf = obuf; obuf = t;
    }
    const float* y = xin;   // final layer output

    k_pool<<<(NND + 31) / 32, 128, 0, stream>>>(y, batch, g);
    k_mlp<<<NG / 4, 128, 0, stream>>>(g, lw1, lb1, lw2, lb2, lw3, lb3, (float*)d_out);
}

// Round 3
// 808.604 us; speedup vs baseline: 3.1023x; 1.6198x over previous
//
#include <hip/hip_runtime.h>

#define NND 50000
#define NE  800000
#define NET 850000   // NE + NND self-loops
#define NG  2048

__device__ __forceinline__ float frelu(float v){ return v > 0.f ? v : 0.f; }

// ---------------- mean of edge_features: block-reduce, 8 atomics/block ----------
__global__ __launch_bounds__(256) void k_mean(const float* __restrict__ ef,
                                              float* __restrict__ acc8){
    __shared__ float red[256];
    int tid = threadIdx.x;
    int i0 = blockIdx.x * 256 + tid;
    int stride = gridDim.x * 256;          // multiple of 8
    float s = 0.f;
    for (int i = i0; i < NE * 8; i += stride) s += ef[i];
    red[tid] = s;
    __syncthreads();
    for (int off = 128; off >= 8; off >>= 1){
        if (tid < off) red[tid] += red[tid + off];
        __syncthreads();
    }
    if (tid < 8) atomicAdd(&acc8[tid], red[tid]);
}

// ---------------- M[3][8][4] and self-loop al_e constants sc[3][4] ---------------
__global__ void k_prep(const float* __restrict__ acc8,
                       const float* __restrict__ We1, const float* __restrict__ ae1,
                       const float* __restrict__ We2, const float* __restrict__ ae2,
                       const float* __restrict__ We3, const float* __restrict__ ae3,
                       float* __restrict__ M, float* __restrict__ sc){
    __shared__ float me[8];
    __shared__ float Ms[96];
    int t = threadIdx.x;
    if (t < 8) me[t] = acc8[t] * (1.0f / NE);
    if (t < 96){
        int l = t >> 5, f = (t >> 2) & 7, h = t & 3;
        const float* We = (l == 0) ? We1 : ((l == 1) ? We2 : We3);
        const float* ae = (l == 0) ? ae1 : ((l == 1) ? ae2 : ae3);
        float s = 0.f;
        for (int c = 0; c < 32; c++) s += We[f * 128 + h * 32 + c] * ae[h * 32 + c];
        M[t] = s; Ms[t] = s;
    }
    __syncthreads();
    if (t < 12){
        int l = t >> 2, h = t & 3;
        float s = 0.f;
        for (int f = 0; f < 8; f++) s += me[f] * Ms[l * 32 + f * 4 + h];
        sc[t] = s;
    }
}

// ------------- h = x @ W  (+ attention logits al_s, al_d) -----------------------
__global__ __launch_bounds__(128) void k_gemm(
        const float* __restrict__ x, const float* __restrict__ W,
        const float* __restrict__ asrc, const float* __restrict__ adst,
        float* __restrict__ h, float* __restrict__ als, float* __restrict__ ald,
        int Fin){
    __shared__ float xs[4 * 128];
    int tid = threadIdx.x;
    int r0 = blockIdx.x * 4;
    for (int i = tid; i < 4 * Fin; i += 128) xs[i] = x[r0 * Fin + i];
    __syncthreads();
    int col = tid;
    float wa_s = asrc[col], wa_d = adst[col];
    float a0 = 0.f, a1 = 0.f, a2 = 0.f, a3 = 0.f;
    for (int k = 0; k < Fin; k++){
        float wv = W[k * 128 + col];
        a0 += xs[k] * wv;
        a1 += xs[Fin + k] * wv;
        a2 += xs[2 * Fin + k] * wv;
        a3 += xs[3 * Fin + k] * wv;
    }
    int head = tid >> 5;
    bool lane0 = ((tid & 31) == 0);
    float accs[4] = {a0, a1, a2, a3};
    for (int r = 0; r < 4; r++){
        float v = accs[r];
        h[(r0 + r) * 128 + col] = v;
        float sv = v * wa_s, dv = v * wa_d;
        for (int off = 16; off > 0; off >>= 1){
            sv += __shfl_down(sv, off, 32);
            dv += __shfl_down(dv, off, 32);
        }
        if (lane0){
            als[(r0 + r) * 4 + head] = sv;
            ald[(r0 + r) * 4 + head] = dv;
        }
    }
}

// ---------------- CSR build: histogram of dst (incl. self-loops) ----------------
__global__ void k_hist(const int* __restrict__ ei, int* __restrict__ cnt){
    int e = blockIdx.x * 256 + threadIdx.x;
    if (e >= NET) return;
    int d = (e < NE) ? ei[NE + e] : (e - NE);
    atomicAdd(&cnt[d], 1);
}

// ---------------- CSR build: exclusive scan (single block) ----------------------
__global__ __launch_bounds__(1024) void k_scan(const int* __restrict__ cnt,
                                               int* __restrict__ rs){
    __shared__ int ls[1024];
    int t = threadIdx.x;
    const int CH = (NND + 1023) / 1024;     // 49
    int base = t * CH;
    int s = 0;
    for (int i = 0; i < CH; i++){
        int idx = base + i;
        if (idx < NND) s += cnt[idx];
    }
    ls[t] = s;
    __syncthreads();
    for (int off = 1; off < 1024; off <<= 1){
        int v = (t >= off) ? ls[t - off] : 0;
        __syncthreads();
        ls[t] += v;
        __syncthreads();
    }
    int run = (t == 0) ? 0 : ls[t - 1];
    for (int i = 0; i < CH; i++){
        int idx = base + i;
        if (idx <= NND) rs[idx] = run;
        if (idx < NND)  run += cnt[idx];
    }
}

// ---------------- CSR build: scatter. Slot 0 of each segment = self-loop --------
__global__ void k_scatter(const int* __restrict__ ei, const int* __restrict__ rs,
                          int* __restrict__ cnt2, int* __restrict__ srcarr,
                          int* __restrict__ slotof){
    int e = blockIdx.x * 256 + threadIdx.x;
    if (e >= NET) return;
    if (e < NE){
        int s = ei[e], d = ei[NE + e];
        int pos = atomicAdd(&cnt2[d], 1) + 1;   // slots 1..deg (0 reserved)
        int slot = rs[d] + pos;
        srcarr[slot] = s;
        slotof[e] = slot;
    } else {
        int n = e - NE;
        srcarr[rs[n]] = n;                      // self-loop at slot 0
    }
}

// ---------------- per-edge attention weights -> CSR slot order ------------------
// grid covers NE real edges + NND self-loops; fully coalesced reads of ef.
__global__ __launch_bounds__(256) void k_weight(
        const int* __restrict__ ei, const float* __restrict__ ef,
        const float4* __restrict__ als4, const float4* __restrict__ ald4,
        const float* __restrict__ Mg, const float* __restrict__ sc4g,
        const int* __restrict__ rs, const int* __restrict__ slotof,
        float4* __restrict__ wS){
    __shared__ float Ms[32];
    __shared__ float Scs[4];
    int t = threadIdx.x;
    if (t < 32) Ms[t] = Mg[t];
    if (t < 4)  Scs[t] = sc4g[t];
    __syncthreads();
    int e = blockIdx.x * 256 + t;
    if (e < NE){
        int s = ei[e], d = ei[NE + e];
        const float4* efp = (const float4*)ef;
        float4 u = efp[e * 2], v = efp[e * 2 + 1];
        float4 A = als4[s], D = ald4[d];
        float4 w;
        float* wp = &w.x;
        const float* Ap = &A.x; const float* Dp = &D.x;
        #pragma unroll
        for (int h = 0; h < 4; h++){
            float ae = u.x * Ms[0 + h]  + u.y * Ms[4 + h]
                     + u.z * Ms[8 + h]  + u.w * Ms[12 + h]
                     + v.x * Ms[16 + h] + v.y * Ms[20 + h]
                     + v.z * Ms[24 + h] + v.w * Ms[28 + h];
            float a = Ap[h] + Dp[h] + ae;
            a = a > 0.f ? a : 0.2f * a;
            wp[h] = __expf(a);
        }
        wS[slotof[e]] = w;
    } else if (e < NE + NND){
        int n = e - NE;
        float4 A = als4[n], D = ald4[n];
        float4 w;
        float* wp = &w.x;
        const float* Ap = &A.x; const float* Dp = &D.x;
        #pragma unroll
        for (int h = 0; h < 4; h++){
            float a = Ap[h] + Dp[h] + Scs[h];
            a = a > 0.f ? a : 0.2f * a;
            wp[h] = __expf(a);
        }
        wS[rs[n]] = w;
    }
}

// ---------------- gather: one wave per node, float2/lane, 4-deep pipeline -------
__global__ __launch_bounds__(256) void k_gather(
        const int* __restrict__ srcarr, const int* __restrict__ rs,
        const float* __restrict__ wS,           // [NET][4]
        const float2* __restrict__ H2,          // h as float2 pairs [NND][64]
        const float* __restrict__ b, float* __restrict__ out){
    int wid  = threadIdx.x >> 6;
    int lane = threadIdx.x & 63;
    int n = blockIdx.x * 4 + wid;               // grid exact: NND/4
    int start = rs[n], end = rs[n + 1];
    int mh = lane >> 4;                         // head of channels (2*lane, 2*lane+1)
    float ax = 0.f, ay = 0.f, accw = 0.f;
    int cnt = end - start;
    int k = 0;
    int s0, s1, s2, s3; float w0, w1, w2, w3;
    if (cnt >= 4){
        int i0 = start;
        s0 = srcarr[i0]; s1 = srcarr[i0+1]; s2 = srcarr[i0+2]; s3 = srcarr[i0+3];
        w0 = wS[i0*4+mh]; w1 = wS[i0*4+4+mh]; w2 = wS[i0*4+8+mh]; w3 = wS[i0*4+12+mh];
    }
    while (k + 4 <= cnt){
        int cs0=s0, cs1=s1, cs2=s2, cs3=s3;
        float cw0=w0, cw1=w1, cw2=w2, cw3=w3;
        k += 4;
        if (k + 4 <= cnt){
            int i0 = start + k;
            s0 = srcarr[i0]; s1 = srcarr[i0+1]; s2 = srcarr[i0+2]; s3 = srcarr[i0+3];
            w0 = wS[i0*4+mh]; w1 = wS[i0*4+4+mh]; w2 = wS[i0*4+8+mh]; w3 = wS[i0*4+12+mh];
        }
        float2 h0 = H2[cs0*64 + lane];
        float2 h1 = H2[cs1*64 + lane];
        float2 h2v = H2[cs2*64 + lane];
        float2 h3 = H2[cs3*64 + lane];
        ax += cw0*h0.x;  ay += cw0*h0.y;
        ax += cw1*h1.x;  ay += cw1*h1.y;
        ax += cw2*h2v.x; ay += cw2*h2v.y;
        ax += cw3*h3.x;  ay += cw3*h3.y;
        accw += cw0 + cw1 + cw2 + cw3;
    }
    for (; k < cnt; k++){
        int i = start + k;
        int s = srcarr[i];
        float w = wS[i*4 + mh];
        float2 hh = H2[s*64 + lane];
        ax += w*hh.x; ay += w*hh.y; accw += w;
    }
    float inv = 1.f / (accw + 1e-16f);
    int c0 = 2 * lane;
    float2 o;
    o.x = frelu(ax * inv + b[c0]);
    o.y = frelu(ay * inv + b[c0 + 1]);
    ((float2*)out)[n * 64 + lane] = o;
}

// ---------------- global add pool: run-length compress sorted batch -------------
__global__ __launch_bounds__(128) void k_pool(const float* __restrict__ y,
                                              const int* __restrict__ batch,
                                              float* __restrict__ g){
    int c = threadIdx.x;
    int n0 = blockIdx.x * 32;
    if (n0 >= NND) return;
    int cur = batch[n0];
    float s = 0.f;
    for (int k = 0; k < 32; k++){
        int n = n0 + k;
        if (n >= NND) break;
        int bg = batch[n];
        if (bg != cur){
            atomicAdd(&g[cur * 128 + c], s);
            s = 0.f; cur = bg;
        }
        s += y[n * 128 + c];
    }
    atomicAdd(&g[cur * 128 + c], s);
}

// ---------------- MLP head: 128->32->32->1 --------------------------------------
__global__ void k_mlp(const float* __restrict__ g,
                      const float* __restrict__ lw1, const float* __restrict__ lb1,
                      const float* __restrict__ lw2, const float* __restrict__ lb2,
                      const float* __restrict__ lw3, const float* __restrict__ lb3,
                      float* __restrict__ out){
    __shared__ float t1[4][32];
    __shared__ float t2[4][32];
    int tid = threadIdx.x, sub = tid >> 5, j = tid & 31;
    int gi = blockIdx.x * 4 + sub;
    const float* gr = g + gi * 128;
    float s = lb1[j];
    for (int c = 0; c < 128; c++) s += gr[c] * lw1[c * 32 + j];
    t1[sub][j] = frelu(s);
    __syncthreads();
    float s2 = lb2[j];
    for (int k = 0; k < 32; k++) s2 += t1[sub][k] * lw2[k * 32 + j];
    t2[sub][j] = frelu(s2);
    __syncthreads();
    if (j == 0){
        float o = lb3[0];
        for (int k = 0; k < 32; k++) o += t2[sub][k] * lw3[k];
        out[gi] = frelu(o);
    }
}

extern "C" void kernel_launch(void* const* d_in, const int* in_sizes, int n_in,
                              void* d_out, int out_size, void* d_ws, size_t ws_size,
                              hipStream_t stream) {
    const float* x     = (const float*)d_in[0];
    const int*   ei    = (const int*)  d_in[1];
    const float* ef    = (const float*)d_in[2];
    const int*   batch = (const int*)  d_in[3];
    const float* W[3]   = {(const float*)d_in[4],  (const float*)d_in[10], (const float*)d_in[16]};
    const float* as_[3] = {(const float*)d_in[5],  (const float*)d_in[11], (const float*)d_in[17]};
    const float* ad_[3] = {(const float*)d_in[6],  (const float*)d_in[12], (const float*)d_in[18]};
    const float* We[3]  = {(const float*)d_in[7],  (const float*)d_in[13], (const float*)d_in[19]};
    const float* ae[3]  = {(const float*)d_in[8],  (const float*)d_in[14], (const float*)d_in[20]};
    const float* b_[3]  = {(const float*)d_in[9],  (const float*)d_in[15], (const float*)d_in[21]};
    const float* lw1 = (const float*)d_in[22]; const float* lb1 = (const float*)d_in[23];
    const float* lw2 = (const float*)d_in[24]; const float* lb2 = (const float*)d_in[25];
    const float* lw3 = (const float*)d_in[26]; const float* lb3 = (const float*)d_in[27];

    float* ws = (float*)d_ws;
    float* Bx   = ws;                      // layer in/out  [NND*128]  (6,400,000)
    float* Hb   = Bx + 6400000;            // h buffer      [NND*128]  (6,400,000)
    float* wSf  = Hb + 6400000;            // weights/slot  [NET*4]    (3,400,000)
    float* als  = wSf + 3400000;           // [NND*4]
    float* ald  = als + 200000;            // [NND*4]
    float* g    = ald + 200000;            // [NG*128] (262,144)
    float* acc8 = g + 262144;              // [8]
    float* M    = acc8 + 8;                // [96]
    float* sc   = M + 96;                  // [12] + 4 pad
    int*   srcarr = (int*)(sc + 16);       // [NET]
    int*   slotof = srcarr + NET;          // [NE]
    int*   rs     = slotof + NE;           // [NND+1] (+pad)
    int*   cnt    = rs + NND + 4;          // [NND]
    int*   cnt2   = cnt + NND;             // [NND]

    hipMemsetAsync(acc8, 0, 8 * sizeof(float), stream);
    hipMemsetAsync(cnt,  0, NND * sizeof(int), stream);
    hipMemsetAsync(cnt2, 0, NND * sizeof(int), stream);
    hipMemsetAsync(g,    0, NG * 128 * sizeof(float), stream);

    k_mean<<<256, 256, 0, stream>>>(ef, acc8);
    k_prep<<<1, 128, 0, stream>>>(acc8, We[0], ae[0], We[1], ae[1], We[2], ae[2], M, sc);

    k_hist<<<(NET + 255) / 256, 256, 0, stream>>>(ei, cnt);
    k_scan<<<1, 1024, 0, stream>>>(cnt, rs);
    k_scatter<<<(NET + 255) / 256, 256, 0, stream>>>(ei, rs, cnt2, srcarr, slotof);

    const float* xin = x;
    for (int l = 0; l < 3; l++){
        int Fin = (l == 0) ? 30 : 128;
        k_gemm<<<NND / 4, 128, 0, stream>>>(xin, W[l], as_[l], ad_[l], Hb, als, ald, Fin);
        k_weight<<<(NE + NND + 255) / 256, 256, 0, stream>>>(
            ei, ef, (const float4*)als, (const float4*)ald,
            M + l * 32, sc + l * 4, rs, slotof, (float4*)wSf);
        k_gather<<<NND / 4, 256, 0, stream>>>(srcarr, rs, wSf, (const float2*)Hb, b_[l], Bx);
        xin = Bx;
    }

    k_pool<<<(NND + 31) / 32, 128, 0, stream>>>(Bx, batch, g);
    k_mlp<<<NG / 4, 128, 0, stream>>>(g, lw1, lb1, lw2, lb2, lw3, lb3, (float*)d_out);
}

// Round 4
// 669.415 us; speedup vs baseline: 3.7473x; 1.2079x over previous
//
#include <hip/hip_runtime.h>

#define NND 50000
#define NE  800000
#define NET 850000   // NE + NND self-loops
#define NG  2048
#define KT  32

__device__ __forceinline__ float frelu(float v){ return v > 0.f ? v : 0.f; }

// ---------------- mean of edge_features: block-reduce, 8 atomics/block ----------
__global__ __launch_bounds__(256) void k_mean(const float* __restrict__ ef,
                                              float* __restrict__ acc8){
    __shared__ float red[256];
    int tid = threadIdx.x;
    int i0 = blockIdx.x * 256 + tid;
    int stride = gridDim.x * 256;
    float s = 0.f;
    for (int i = i0; i < NE * 8; i += stride) s += ef[i];
    red[tid] = s;
    __syncthreads();
    for (int off = 128; off >= 8; off >>= 1){
        if (tid < off) red[tid] += red[tid + off];
        __syncthreads();
    }
    if (tid < 8) atomicAdd(&acc8[tid], red[tid]);
}

// ---------------- M[3][8][4] and self-loop al_e constants sc[3][4] ---------------
__global__ void k_prep(const float* __restrict__ acc8,
                       const float* __restrict__ We1, const float* __restrict__ ae1,
                       const float* __restrict__ We2, const float* __restrict__ ae2,
                       const float* __restrict__ We3, const float* __restrict__ ae3,
                       float* __restrict__ M, float* __restrict__ sc){
    __shared__ float me[8];
    __shared__ float Ms[96];
    int t = threadIdx.x;
    if (t < 8) me[t] = acc8[t] * (1.0f / NE);
    if (t < 96){
        int l = t >> 5, f = (t >> 2) & 7, h = t & 3;
        const float* We = (l == 0) ? We1 : ((l == 1) ? We2 : We3);
        const float* ae = (l == 0) ? ae1 : ((l == 1) ? ae2 : ae3);
        float s = 0.f;
        for (int c = 0; c < 32; c++) s += We[f * 128 + h * 32 + c] * ae[h * 32 + c];
        M[t] = s; Ms[t] = s;
    }
    __syncthreads();
    if (t < 12){
        int l = t >> 2, h = t & 3;
        float s = 0.f;
        for (int f = 0; f < 8; f++) s += me[f] * Ms[l * 32 + f * 4 + h];
        sc[t] = s;
    }
}

// ------------- tiled GEMM: h = x @ W, fused als/ald epilogue --------------------
// block 256 = 32 colgroups x 8 rowgroups; thread owns 4 rows x 4 cols registers.
__global__ __launch_bounds__(256) void k_gemm(
        const float* __restrict__ x, const float* __restrict__ W,
        const float* __restrict__ asrc, const float* __restrict__ adst,
        float* __restrict__ h, float* __restrict__ als, float* __restrict__ ald,
        int Fin){
    __shared__ float Ws[KT * 128];       // [k][col]
    __shared__ float xst[KT * 36];       // [k][row], stride 36 (16B-aligned rows)
    int t  = threadIdx.x;
    int cg = t & 31;                     // cols 4cg..4cg+3
    int rg = t >> 5;                     // rows r0+4rg..r0+4rg+3
    int r0 = blockIdx.x * 32;
    float acc[4][4] = {{0.f}};
    int nch = (Fin + KT - 1) / KT;
    for (int ch = 0; ch < nch; ch++){
        int k0 = ch * KT;
        // stage W chunk (vectorized, coalesced)
        {
            const float4* Wv = (const float4*)(W + k0 * 128);
            float4* Wsv = (float4*)Ws;
            int lim = (Fin - k0 >= KT ? KT : Fin - k0) * 32;   // valid float4s
            for (int i = t; i < KT * 32; i += 256)
                Wsv[i] = (i < lim) ? Wv[i] : make_float4(0.f, 0.f, 0.f, 0.f);
        }
        // stage x chunk transposed: xst[kk][r]
        for (int i = t; i < 32 * KT; i += 256){
            int r = i >> 5, kk = i & 31;
            int gr = r0 + r;
            float v = 0.f;
            if (gr < NND && (k0 + kk) < Fin) v = x[gr * Fin + k0 + kk];
            xst[kk * 36 + r] = v;
        }
        __syncthreads();
        #pragma unroll 8
        for (int k = 0; k < KT; k++){
            float4 xv = *(const float4*)&xst[k * 36 + rg * 4];   // broadcast
            float4 wv = *(const float4*)&Ws[k * 128 + cg * 4];   // conflict-free
            acc[0][0] += xv.x * wv.x; acc[0][1] += xv.x * wv.y;
            acc[0][2] += xv.x * wv.z; acc[0][3] += xv.x * wv.w;
            acc[1][0] += xv.y * wv.x; acc[1][1] += xv.y * wv.y;
            acc[1][2] += xv.y * wv.z; acc[1][3] += xv.y * wv.w;
            acc[2][0] += xv.z * wv.x; acc[2][1] += xv.z * wv.y;
            acc[2][2] += xv.z * wv.z; acc[2][3] += xv.z * wv.w;
            acc[3][0] += xv.w * wv.x; acc[3][1] += xv.w * wv.y;
            acc[3][2] += xv.w * wv.z; acc[3][3] += xv.w * wv.w;
        }
        __syncthreads();
    }
    // epilogue: store h, reduce attention logits per head (8 lanes = 1 head)
    float4 av = *(const float4*)&asrc[cg * 4];
    float4 dv = *(const float4*)&adst[cg * 4];
    int head = cg >> 3;
    bool leader = ((cg & 7) == 0);
    #pragma unroll
    for (int r = 0; r < 4; r++){
        int gr = r0 + rg * 4 + r;
        float4 o = make_float4(acc[r][0], acc[r][1], acc[r][2], acc[r][3]);
        if (gr < NND) *(float4*)&h[gr * 128 + cg * 4] = o;
        float sv = o.x * av.x + o.y * av.y + o.z * av.z + o.w * av.w;
        float sd = o.x * dv.x + o.y * dv.y + o.z * dv.z + o.w * dv.w;
        sv += __shfl_down(sv, 4, 64); sd += __shfl_down(sd, 4, 64);
        sv += __shfl_down(sv, 2, 64); sd += __shfl_down(sd, 2, 64);
        sv += __shfl_down(sv, 1, 64); sd += __shfl_down(sd, 1, 64);
        if (leader && gr < NND){
            als[gr * 4 + head] = sv;
            ald[gr * 4 + head] = sd;
        }
    }
}

// ---------------- CSR build: histogram of dst (incl. self-loops) ----------------
__global__ void k_hist(const int* __restrict__ ei, int* __restrict__ cnt){
    int e = blockIdx.x * 256 + threadIdx.x;
    if (e >= NET) return;
    int d = (e < NE) ? ei[NE + e] : (e - NE);
    atomicAdd(&cnt[d], 1);
}

// ---------------- CSR build: exclusive scan (single block) ----------------------
__global__ __launch_bounds__(1024) void k_scan(const int* __restrict__ cnt,
                                               int* __restrict__ rs){
    __shared__ int ls[1024];
    int t = threadIdx.x;
    const int CH = (NND + 1023) / 1024;
    int base = t * CH;
    int s = 0;
    for (int i = 0; i < CH; i++){
        int idx = base + i;
        if (idx < NND) s += cnt[idx];
    }
    ls[t] = s;
    __syncthreads();
    for (int off = 1; off < 1024; off <<= 1){
        int v = (t >= off) ? ls[t - off] : 0;
        __syncthreads();
        ls[t] += v;
        __syncthreads();
    }
    int run = (t == 0) ? 0 : ls[t - 1];
    for (int i = 0; i < CH; i++){
        int idx = base + i;
        if (idx <= NND) rs[idx] = run;
        if (idx < NND)  run += cnt[idx];
    }
}

// ---------------- CSR build: scatter. Slot 0 of each segment = self-loop --------
__global__ void k_scatter(const int* __restrict__ ei, const int* __restrict__ rs,
                          int* __restrict__ cnt2, int* __restrict__ srcarr,
                          int* __restrict__ slotof){
    int e = blockIdx.x * 256 + threadIdx.x;
    if (e >= NET) return;
    if (e < NE){
        int s = ei[e], d = ei[NE + e];
        int pos = atomicAdd(&cnt2[d], 1) + 1;
        int slot = rs[d] + pos;
        srcarr[slot] = s;
        slotof[e] = slot;
    } else {
        int n = e - NE;
        srcarr[rs[n]] = n;
    }
}

// ---------------- per-edge attention weights -> CSR slot order ------------------
__global__ __launch_bounds__(256) void k_weight(
        const int* __restrict__ ei, const float* __restrict__ ef,
        const float4* __restrict__ als4, const float4* __restrict__ ald4,
        const float* __restrict__ Mg, const float* __restrict__ sc4g,
        const int* __restrict__ rs, const int* __restrict__ slotof,
        float4* __restrict__ wS){
    __shared__ float Ms[32];
    __shared__ float Scs[4];
    int t = threadIdx.x;
    if (t < 32) Ms[t] = Mg[t];
    if (t < 4)  Scs[t] = sc4g[t];
    __syncthreads();
    int e = blockIdx.x * 256 + t;
    if (e < NE){
        int s = ei[e], d = ei[NE + e];
        const float4* efp = (const float4*)ef;
        float4 u = efp[e * 2], v = efp[e * 2 + 1];
        float4 A = als4[s], D = ald4[d];
        float4 w;
        float* wp = &w.x;
        const float* Ap = &A.x; const float* Dp = &D.x;
        #pragma unroll
        for (int h = 0; h < 4; h++){
            float ae = u.x * Ms[0 + h]  + u.y * Ms[4 + h]
                     + u.z * Ms[8 + h]  + u.w * Ms[12 + h]
                     + v.x * Ms[16 + h] + v.y * Ms[20 + h]
                     + v.z * Ms[24 + h] + v.w * Ms[28 + h];
            float a = Ap[h] + Dp[h] + ae;
            a = a > 0.f ? a : 0.2f * a;
            wp[h] = __expf(a);
        }
        wS[slotof[e]] = w;
    } else if (e < NE + NND){
        int n = e - NE;
        float4 A = als4[n], D = ald4[n];
        float4 w;
        float* wp = &w.x;
        const float* Ap = &A.x; const float* Dp = &D.x;
        #pragma unroll
        for (int h = 0; h < 4; h++){
            float a = Ap[h] + Dp[h] + Scs[h];
            a = a > 0.f ? a : 0.2f * a;
            wp[h] = __expf(a);
        }
        wS[rs[n]] = w;
    }
}

// ---------------- gather: one wave per node, float2/lane, 4-deep pipeline -------
__global__ __launch_bounds__(256) void k_gather(
        const int* __restrict__ srcarr, const int* __restrict__ rs,
        const float* __restrict__ wS,
        const float2* __restrict__ H2,
        const float* __restrict__ b, float* __restrict__ out){
    int wid  = threadIdx.x >> 6;
    int lane = threadIdx.x & 63;
    int n = blockIdx.x * 4 + wid;
    int start = rs[n], end = rs[n + 1];
    int mh = lane >> 4;
    float ax = 0.f, ay = 0.f, accw = 0.f;
    int cnt = end - start;
    int k = 0;
    int s0, s1, s2, s3; float w0, w1, w2, w3;
    if (cnt >= 4){
        int i0 = start;
        s0 = srcarr[i0]; s1 = srcarr[i0+1]; s2 = srcarr[i0+2]; s3 = srcarr[i0+3];
        w0 = wS[i0*4+mh]; w1 = wS[i0*4+4+mh]; w2 = wS[i0*4+8+mh]; w3 = wS[i0*4+12+mh];
    }
    while (k + 4 <= cnt){
        int cs0=s0, cs1=s1, cs2=s2, cs3=s3;
        float cw0=w0, cw1=w1, cw2=w2, cw3=w3;
        k += 4;
        if (k + 4 <= cnt){
            int i0 = start + k;
            s0 = srcarr[i0]; s1 = srcarr[i0+1]; s2 = srcarr[i0+2]; s3 = srcarr[i0+3];
            w0 = wS[i0*4+mh]; w1 = wS[i0*4+4+mh]; w2 = wS[i0*4+8+mh]; w3 = wS[i0*4+12+mh];
        }
        float2 h0 = H2[cs0*64 + lane];
        float2 h1 = H2[cs1*64 + lane];
        float2 h2v = H2[cs2*64 + lane];
        float2 h3 = H2[cs3*64 + lane];
        ax += cw0*h0.x;  ay += cw0*h0.y;
        ax += cw1*h1.x;  ay += cw1*h1.y;
        ax += cw2*h2v.x; ay += cw2*h2v.y;
        ax += cw3*h3.x;  ay += cw3*h3.y;
        accw += cw0 + cw1 + cw2 + cw3;
    }
    for (; k < cnt; k++){
        int i = start + k;
        int s = srcarr[i];
        float w = wS[i*4 + mh];
        float2 hh = H2[s*64 + lane];
        ax += w*hh.x; ay += w*hh.y; accw += w;
    }
    float inv = 1.f / (accw + 1e-16f);
    int c0 = 2 * lane;
    float2 o;
    o.x = frelu(ax * inv + b[c0]);
    o.y = frelu(ay * inv + b[c0 + 1]);
    ((float2*)out)[n * 64 + lane] = o;
}

// ---------------- global add pool: run-length compress sorted batch -------------
__global__ __launch_bounds__(128) void k_pool(const float* __restrict__ y,
                                              const int* __restrict__ batch,
                                              float* __restrict__ g){
    int c = threadIdx.x;
    int n0 = blockIdx.x * 32;
    if (n0 >= NND) return;
    int cur = batch[n0];
    float s = 0.f;
    for (int k = 0; k < 32; k++){
        int n = n0 + k;
        if (n >= NND) break;
        int bg = batch[n];
        if (bg != cur){
            atomicAdd(&g[cur * 128 + c], s);
            s = 0.f; cur = bg;
        }
        s += y[n * 128 + c];
    }
    atomicAdd(&g[cur * 128 + c], s);
}

// ---------------- MLP head: 128->32->32->1 --------------------------------------
__global__ void k_mlp(const float* __restrict__ g,
                      const float* __restrict__ lw1, const float* __restrict__ lb1,
                      const float* __restrict__ lw2, const float* __restrict__ lb2,
                      const float* __restrict__ lw3, const float* __restrict__ lb3,
                      float* __restrict__ out){
    __shared__ float t1[4][32];
    __shared__ float t2[4][32];
    int tid = threadIdx.x, sub = tid >> 5, j = tid & 31;
    int gi = blockIdx.x * 4 + sub;
    const float* gr = g + gi * 128;
    float s = lb1[j];
    for (int c = 0; c < 128; c++) s += gr[c] * lw1[c * 32 + j];
    t1[sub][j] = frelu(s);
    __syncthreads();
    float s2 = lb2[j];
    for (int k = 0; k < 32; k++) s2 += t1[sub][k] * lw2[k * 32 + j];
    t2[sub][j] = frelu(s2);
    __syncthreads();
    if (j == 0){
        float o = lb3[0];
        for (int k = 0; k < 32; k++) o += t2[sub][k] * lw3[k];
        out[gi] = frelu(o);
    }
}

extern "C" void kernel_launch(void* const* d_in, const int* in_sizes, int n_in,
                              void* d_out, int out_size, void* d_ws, size_t ws_size,
                              hipStream_t stream) {
    const float* x     = (const float*)d_in[0];
    const int*   ei    = (const int*)  d_in[1];
    const float* ef    = (const float*)d_in[2];
    const int*   batch = (const int*)  d_in[3];
    const float* W[3]   = {(const float*)d_in[4],  (const float*)d_in[10], (const float*)d_in[16]};
    const float* as_[3] = {(const float*)d_in[5],  (const float*)d_in[11], (const float*)d_in[17]};
    const float* ad_[3] = {(const float*)d_in[6],  (const float*)d_in[12], (const float*)d_in[18]};
    const float* We[3]  = {(const float*)d_in[7],  (const float*)d_in[13], (const float*)d_in[19]};
    const float* ae[3]  = {(const float*)d_in[8],  (const float*)d_in[14], (const float*)d_in[20]};
    const float* b_[3]  = {(const float*)d_in[9],  (const float*)d_in[15], (const float*)d_in[21]};
    const float* lw1 = (const float*)d_in[22]; const float* lb1 = (const float*)d_in[23];
    const float* lw2 = (const float*)d_in[24]; const float* lb2 = (const float*)d_in[25];
    const float* lw3 = (const float*)d_in[26]; const float* lb3 = (const float*)d_in[27];

    float* ws = (float*)d_ws;
    float* Bx   = ws;                      // layer in/out  [NND*128]
    float* Hb   = Bx + 6400000;            // h buffer      [NND*128]
    float* wSf  = Hb + 6400000;            // weights/slot  [NET*4]
    float* als  = wSf + 3400000;           // [NND*4]
    float* ald  = als + 200000;            // [NND*4]
    float* g    = ald + 200000;            // [NG*128]
    float* acc8 = g + 262144;              // [8]
    float* M    = acc8 + 8;                // [96]
    float* sc   = M + 96;                  // [12] + pad
    int*   srcarr = (int*)(sc + 16);       // [NET]
    int*   slotof = srcarr + NET;          // [NE]
    int*   rs     = slotof + NE;           // [NND+1] (+pad)
    int*   cnt    = rs + NND + 4;          // [NND]
    int*   cnt2   = cnt + NND;             // [NND]

    hipMemsetAsync(acc8, 0, 8 * sizeof(float), stream);
    hipMemsetAsync(cnt,  0, NND * sizeof(int), stream);
    hipMemsetAsync(cnt2, 0, NND * sizeof(int), stream);
    hipMemsetAsync(g,    0, NG * 128 * sizeof(float), stream);

    k_mean<<<256, 256, 0, stream>>>(ef, acc8);
    k_prep<<<1, 128, 0, stream>>>(acc8, We[0], ae[0], We[1], ae[1], We[2], ae[2], M, sc);

    k_hist<<<(NET + 255) / 256, 256, 0, stream>>>(ei, cnt);
    k_scan<<<1, 1024, 0, stream>>>(cnt, rs);
    k_scatter<<<(NET + 255) / 256, 256, 0, stream>>>(ei, rs, cnt2, srcarr, slotof);

    const float* xin = x;
    for (int l = 0; l < 3; l++){
        int Fin = (l == 0) ? 30 : 128;
        k_gemm<<<(NND + 31) / 32, 256, 0, stream>>>(xin, W[l], as_[l], ad_[l],
                                                    Hb, als, ald, Fin);
        k_weight<<<(NE + NND + 255) / 256, 256, 0, stream>>>(
            ei, ef, (const float4*)als, (const float4*)ald,
            M + l * 32, sc + l * 4, rs, slotof, (float4*)wSf);
        k_gather<<<NND / 4, 256, 0, stream>>>(srcarr, rs, wSf, (const float2*)Hb, b_[l], Bx);
        xin = Bx;
    }

    k_pool<<<(NND + 31) / 32, 128, 0, stream>>>(Bx, batch, g);
    k_mlp<<<NG / 4, 128, 0, stream>>>(g, lw1, lb1, lw2, lb2, lw3, lb3, (float*)d_out);
}

// Round 5
// 593.886 us; speedup vs baseline: 4.2239x; 1.1272x over previous
//
#include <hip/hip_runtime.h>

#define NND 50000
#define NE  800000
#define NET 850000   // NE + NND self-loops
#define NG  2048
#define KT  32
#define SCB 196      // scan blocks = ceil(NND/256)

__device__ __forceinline__ float frelu(float v){ return v > 0.f ? v : 0.f; }

// ---------------- mean of edge_features: block-reduce, 8 atomics/block ----------
__global__ __launch_bounds__(256) void k_mean(const float* __restrict__ ef,
                                              float* __restrict__ acc8){
    __shared__ float red[256];
    int tid = threadIdx.x;
    int i0 = blockIdx.x * 256 + tid;
    int stride = gridDim.x * 256;
    float s = 0.f;
    for (int i = i0; i < NE * 8; i += stride) s += ef[i];
    red[tid] = s;
    __syncthreads();
    for (int off = 128; off >= 8; off >>= 1){
        if (tid < off) red[tid] += red[tid + off];
        __syncthreads();
    }
    if (tid < 8) atomicAdd(&acc8[tid], red[tid]);
}

// ---------------- M[3][8][4] and self-loop al_e constants sc[3][4] ---------------
__global__ void k_prep(const float* __restrict__ acc8,
                       const float* __restrict__ We1, const float* __restrict__ ae1,
                       const float* __restrict__ We2, const float* __restrict__ ae2,
                       const float* __restrict__ We3, const float* __restrict__ ae3,
                       float* __restrict__ M, float* __restrict__ sc){
    __shared__ float me[8];
    __shared__ float Ms[96];
    int t = threadIdx.x;
    if (t < 8) me[t] = acc8[t] * (1.0f / NE);
    if (t < 96){
        int l = t >> 5, f = (t >> 2) & 7, h = t & 3;
        const float* We = (l == 0) ? We1 : ((l == 1) ? We2 : We3);
        const float* ae = (l == 0) ? ae1 : ((l == 1) ? ae2 : ae3);
        float s = 0.f;
        for (int c = 0; c < 32; c++) s += We[f * 128 + h * 32 + c] * ae[h * 32 + c];
        M[t] = s; Ms[t] = s;
    }
    __syncthreads();
    if (t < 12){
        int l = t >> 2, h = t & 3;
        float s = 0.f;
        for (int f = 0; f < 8; f++) s += me[f] * Ms[l * 32 + f * 4 + h];
        sc[t] = s;
    }
}

// ------------- tiled GEMM: h = x @ W, fused als/ald epilogue --------------------
__global__ __launch_bounds__(256) void k_gemm(
        const float* __restrict__ x, const float* __restrict__ W,
        const float* __restrict__ asrc, const float* __restrict__ adst,
        float* __restrict__ h, float* __restrict__ als, float* __restrict__ ald,
        int Fin){
    __shared__ float Ws[KT * 128];       // [k][col]
    __shared__ float xst[KT * 36];       // [k][row], stride 36
    int t  = threadIdx.x;
    int cg = t & 31;
    int rg = t >> 5;
    int r0 = blockIdx.x * 32;
    float acc[4][4] = {{0.f}};
    int nch = (Fin + KT - 1) / KT;
    for (int ch = 0; ch < nch; ch++){
        int k0 = ch * KT;
        {
            const float4* Wv = (const float4*)(W + k0 * 128);
            float4* Wsv = (float4*)Ws;
            int lim = (Fin - k0 >= KT ? KT : Fin - k0) * 32;
            for (int i = t; i < KT * 32; i += 256)
                Wsv[i] = (i < lim) ? Wv[i] : make_float4(0.f, 0.f, 0.f, 0.f);
        }
        for (int i = t; i < 32 * KT; i += 256){
            int r = i >> 5, kk = i & 31;
            int gr = r0 + r;
            float v = 0.f;
            if (gr < NND && (k0 + kk) < Fin) v = x[gr * Fin + k0 + kk];
            xst[kk * 36 + r] = v;
        }
        __syncthreads();
        #pragma unroll 8
        for (int k = 0; k < KT; k++){
            float4 xv = *(const float4*)&xst[k * 36 + rg * 4];
            float4 wv = *(const float4*)&Ws[k * 128 + cg * 4];
            acc[0][0] += xv.x * wv.x; acc[0][1] += xv.x * wv.y;
            acc[0][2] += xv.x * wv.z; acc[0][3] += xv.x * wv.w;
            acc[1][0] += xv.y * wv.x; acc[1][1] += xv.y * wv.y;
            acc[1][2] += xv.y * wv.z; acc[1][3] += xv.y * wv.w;
            acc[2][0] += xv.z * wv.x; acc[2][1] += xv.z * wv.y;
            acc[2][2] += xv.z * wv.z; acc[2][3] += xv.z * wv.w;
            acc[3][0] += xv.w * wv.x; acc[3][1] += xv.w * wv.y;
            acc[3][2] += xv.w * wv.z; acc[3][3] += xv.w * wv.w;
        }
        __syncthreads();
    }
    float4 av = *(const float4*)&asrc[cg * 4];
    float4 dv = *(const float4*)&adst[cg * 4];
    int head = cg >> 3;
    bool leader = ((cg & 7) == 0);
    #pragma unroll
    for (int r = 0; r < 4; r++){
        int gr = r0 + rg * 4 + r;
        float4 o = make_float4(acc[r][0], acc[r][1], acc[r][2], acc[r][3]);
        if (gr < NND) *(float4*)&h[gr * 128 + cg * 4] = o;
        float sv = o.x * av.x + o.y * av.y + o.z * av.z + o.w * av.w;
        float sd = o.x * dv.x + o.y * dv.y + o.z * dv.z + o.w * dv.w;
        sv += __shfl_down(sv, 4, 64); sd += __shfl_down(sd, 4, 64);
        sv += __shfl_down(sv, 2, 64); sd += __shfl_down(sd, 2, 64);
        sv += __shfl_down(sv, 1, 64); sd += __shfl_down(sd, 1, 64);
        if (leader && gr < NND){
            als[gr * 4 + head] = sv;
            ald[gr * 4 + head] = sd;
        }
    }
}

// ---------------- CSR build: histogram of dst (incl. self-loops) ----------------
__global__ void k_hist(const int* __restrict__ ei, int* __restrict__ cnt){
    int e = blockIdx.x * 256 + threadIdx.x;
    if (e >= NET) return;
    int d = (e < NE) ? ei[NE + e] : (e - NE);
    atomicAdd(&cnt[d], 1);
}

// ---------------- scan phase 1: per-block sums ----------------------------------
__global__ __launch_bounds__(256) void k_scan1(const int* __restrict__ cnt,
                                               int* __restrict__ bsum){
    __shared__ int red[256];
    int t = threadIdx.x;
    int idx = blockIdx.x * 256 + t;
    red[t] = (idx < NND) ? cnt[idx] : 0;
    __syncthreads();
    for (int off = 128; off > 0; off >>= 1){
        if (t < off) red[t] += red[t + off];
        __syncthreads();
    }
    if (t == 0) bsum[blockIdx.x] = red[0];
}

// ---------------- scan phase 2: scan the 196 block sums (1 tiny block) ----------
__global__ __launch_bounds__(256) void k_scan2(const int* __restrict__ bsum,
                                               int* __restrict__ boff,
                                               int* __restrict__ rs){
    __shared__ int ls[256];
    int t = threadIdx.x;
    int v = (t < SCB) ? bsum[t] : 0;
    ls[t] = v;
    __syncthreads();
    for (int off = 1; off < 256; off <<= 1){
        int u = (t >= off) ? ls[t - off] : 0;
        __syncthreads();
        ls[t] += u;
        __syncthreads();
    }
    if (t < SCB) boff[t] = ls[t] - bsum[t];       // exclusive offset per block
    if (t == 0)  rs[NND] = ls[255];               // total = NET
}

// ---------------- scan phase 3: per-block exclusive scan + offset ---------------
__global__ __launch_bounds__(256) void k_scan3(const int* __restrict__ cnt,
                                               const int* __restrict__ boff,
                                               int* __restrict__ rs){
    __shared__ int ls[256];
    int t = threadIdx.x;
    int idx = blockIdx.x * 256 + t;
    int v = (idx < NND) ? cnt[idx] : 0;
    ls[t] = v;
    __syncthreads();
    for (int off = 1; off < 256; off <<= 1){
        int u = (t >= off) ? ls[t - off] : 0;
        __syncthreads();
        ls[t] += u;
        __syncthreads();
    }
    if (idx < NND) rs[idx] = boff[blockIdx.x] + ls[t] - v;
}

// ---------------- CSR build: scatter. Slot 0 of each segment = self-loop --------
__global__ void k_scatter(const int* __restrict__ ei, const int* __restrict__ rs,
                          int* __restrict__ cnt2, int* __restrict__ srcarr,
                          int* __restrict__ slotof){
    int e = blockIdx.x * 256 + threadIdx.x;
    if (e >= NET) return;
    if (e < NE){
        int s = ei[e], d = ei[NE + e];
        int pos = atomicAdd(&cnt2[d], 1) + 1;
        int slot = rs[d] + pos;
        srcarr[slot] = s;
        slotof[e] = slot;
    } else {
        int n = e - NE;
        srcarr[rs[n]] = n;
    }
}

// ---------------- per-edge attention weights -> CSR slot order ------------------
__global__ __launch_bounds__(256) void k_weight(
        const int* __restrict__ ei, const float* __restrict__ ef,
        const float4* __restrict__ als4, const float4* __restrict__ ald4,
        const float* __restrict__ Mg, const float* __restrict__ sc4g,
        const int* __restrict__ rs, const int* __restrict__ slotof,
        float4* __restrict__ wS){
    __shared__ float Ms[32];
    __shared__ float Scs[4];
    int t = threadIdx.x;
    if (t < 32) Ms[t] = Mg[t];
    if (t < 4)  Scs[t] = sc4g[t];
    __syncthreads();
    int e = blockIdx.x * 256 + t;
    if (e < NE){
        int s = ei[e], d = ei[NE + e];
        const float4* efp = (const float4*)ef;
        float4 u = efp[e * 2], v = efp[e * 2 + 1];
        float4 A = als4[s], D = ald4[d];
        float4 w;
        float* wp = &w.x;
        const float* Ap = &A.x; const float* Dp = &D.x;
        #pragma unroll
        for (int h = 0; h < 4; h++){
            float ae = u.x * Ms[0 + h]  + u.y * Ms[4 + h]
                     + u.z * Ms[8 + h]  + u.w * Ms[12 + h]
                     + v.x * Ms[16 + h] + v.y * Ms[20 + h]
                     + v.z * Ms[24 + h] + v.w * Ms[28 + h];
            float a = Ap[h] + Dp[h] + ae;
            a = a > 0.f ? a : 0.2f * a;
            wp[h] = __expf(a);
        }
        wS[slotof[e]] = w;
    } else if (e < NE + NND){
        int n = e - NE;
        float4 A = als4[n], D = ald4[n];
        float4 w;
        float* wp = &w.x;
        const float* Ap = &A.x; const float* Dp = &D.x;
        #pragma unroll
        for (int h = 0; h < 4; h++){
            float a = Ap[h] + Dp[h] + Scs[h];
            a = a > 0.f ? a : 0.2f * a;
            wp[h] = __expf(a);
        }
        wS[rs[n]] = w;
    }
}

// ---------------- gather: one wave per node, float2/lane, 4-deep pipeline -------
__global__ __launch_bounds__(256) void k_gather(
        const int* __restrict__ srcarr, const int* __restrict__ rs,
        const float* __restrict__ wS,
        const float2* __restrict__ H2,
        const float* __restrict__ b, float* __restrict__ out){
    int wid  = threadIdx.x >> 6;
    int lane = threadIdx.x & 63;
    int n = blockIdx.x * 4 + wid;
    int start = rs[n], end = rs[n + 1];
    int mh = lane >> 4;
    float ax = 0.f, ay = 0.f, accw = 0.f;
    int cnt = end - start;
    int k = 0;
    int s0, s1, s2, s3; float w0, w1, w2, w3;
    if (cnt >= 4){
        int i0 = start;
        s0 = srcarr[i0]; s1 = srcarr[i0+1]; s2 = srcarr[i0+2]; s3 = srcarr[i0+3];
        w0 = wS[i0*4+mh]; w1 = wS[i0*4+4+mh]; w2 = wS[i0*4+8+mh]; w3 = wS[i0*4+12+mh];
    }
    while (k + 4 <= cnt){
        int cs0=s0, cs1=s1, cs2=s2, cs3=s3;
        float cw0=w0, cw1=w1, cw2=w2, cw3=w3;
        k += 4;
        if (k + 4 <= cnt){
            int i0 = start + k;
            s0 = srcarr[i0]; s1 = srcarr[i0+1]; s2 = srcarr[i0+2]; s3 = srcarr[i0+3];
            w0 = wS[i0*4+mh]; w1 = wS[i0*4+4+mh]; w2 = wS[i0*4+8+mh]; w3 = wS[i0*4+12+mh];
        }
        float2 h0 = H2[cs0*64 + lane];
        float2 h1 = H2[cs1*64 + lane];
        float2 h2v = H2[cs2*64 + lane];
        float2 h3 = H2[cs3*64 + lane];
        ax += cw0*h0.x;  ay += cw0*h0.y;
        ax += cw1*h1.x;  ay += cw1*h1.y;
        ax += cw2*h2v.x; ay += cw2*h2v.y;
        ax += cw3*h3.x;  ay += cw3*h3.y;
        accw += cw0 + cw1 + cw2 + cw3;
    }
    for (; k < cnt; k++){
        int i = start + k;
        int s = srcarr[i];
        float w = wS[i*4 + mh];
        float2 hh = H2[s*64 + lane];
        ax += w*hh.x; ay += w*hh.y; accw += w;
    }
    float inv = 1.f / (accw + 1e-16f);
    int c0 = 2 * lane;
    float2 o;
    o.x = frelu(ax * inv + b[c0]);
    o.y = frelu(ay * inv + b[c0 + 1]);
    ((float2*)out)[n * 64 + lane] = o;
}

// ---------------- global add pool: run-length compress sorted batch -------------
__global__ __launch_bounds__(128) void k_pool(const float* __restrict__ y,
                                              const int* __restrict__ batch,
                                              float* __restrict__ g){
    int c = threadIdx.x;
    int n0 = blockIdx.x * 32;
    if (n0 >= NND) return;
    int cur = batch[n0];
    float s = 0.f;
    for (int k = 0; k < 32; k++){
        int n = n0 + k;
        if (n >= NND) break;
        int bg = batch[n];
        if (bg != cur){
            atomicAdd(&g[cur * 128 + c], s);
            s = 0.f; cur = bg;
        }
        s += y[n * 128 + c];
    }
    atomicAdd(&g[cur * 128 + c], s);
}

// ---------------- MLP head: 128->32->32->1 --------------------------------------
__global__ void k_mlp(const float* __restrict__ g,
                      const float* __restrict__ lw1, const float* __restrict__ lb1,
                      const float* __restrict__ lw2, const float* __restrict__ lb2,
                      const float* __restrict__ lw3, const float* __restrict__ lb3,
                      float* __restrict__ out){
    __shared__ float t1[4][32];
    __shared__ float t2[4][32];
    int tid = threadIdx.x, sub = tid >> 5, j = tid & 31;
    int gi = blockIdx.x * 4 + sub;
    const float* gr = g + gi * 128;
    float s = lb1[j];
    for (int c = 0; c < 128; c++) s += gr[c] * lw1[c * 32 + j];
    t1[sub][j] = frelu(s);
    __syncthreads();
    float s2 = lb2[j];
    for (int k = 0; k < 32; k++) s2 += t1[sub][k] * lw2[k * 32 + j];
    t2[sub][j] = frelu(s2);
    __syncthreads();
    if (j == 0){
        float o = lb3[0];
        for (int k = 0; k < 32; k++) o += t2[sub][k] * lw3[k];
        out[gi] = frelu(o);
    }
}

extern "C" void kernel_launch(void* const* d_in, const int* in_sizes, int n_in,
                              void* d_out, int out_size, void* d_ws, size_t ws_size,
                              hipStream_t stream) {
    const float* x     = (const float*)d_in[0];
    const int*   ei    = (const int*)  d_in[1];
    const float* ef    = (const float*)d_in[2];
    const int*   batch = (const int*)  d_in[3];
    const float* W[3]   = {(const float*)d_in[4],  (const float*)d_in[10], (const float*)d_in[16]};
    const float* as_[3] = {(const float*)d_in[5],  (const float*)d_in[11], (const float*)d_in[17]};
    const float* ad_[3] = {(const float*)d_in[6],  (const float*)d_in[12], (const float*)d_in[18]};
    const float* We[3]  = {(const float*)d_in[7],  (const float*)d_in[13], (const float*)d_in[19]};
    const float* ae[3]  = {(const float*)d_in[8],  (const float*)d_in[14], (const float*)d_in[20]};
    const float* b_[3]  = {(const float*)d_in[9],  (const float*)d_in[15], (const float*)d_in[21]};
    const float* lw1 = (const float*)d_in[22]; const float* lb1 = (const float*)d_in[23];
    const float* lw2 = (const float*)d_in[24]; const float* lb2 = (const float*)d_in[25];
    const float* lw3 = (const float*)d_in[26]; const float* lb3 = (const float*)d_in[27];

    float* ws = (float*)d_ws;
    float* Bx   = ws;                      // layer in/out  [NND*128]
    float* Hb   = Bx + 6400000;            // h buffer      [NND*128]
    float* wSf  = Hb + 6400000;            // weights/slot  [NET*4]
    float* als  = wSf + 3400000;           // [NND*4]
    float* ald  = als + 200000;            // [NND*4]
    float* g    = ald + 200000;            // [NG*128]
    float* acc8 = g + 262144;              // [8]
    float* M    = acc8 + 8;                // [96]
    float* sc   = M + 96;                  // [12] + pad
    int*   srcarr = (int*)(sc + 16);       // [NET]
    int*   slotof = srcarr + NET;          // [NE]
    int*   rs     = slotof + NE;           // [NND+1] (+pad)
    int*   cnt    = rs + NND + 4;          // [NND]
    int*   cnt2   = cnt + NND;             // [NND]
    int*   bsum   = cnt2 + NND;            // [SCB]
    int*   boff   = bsum + SCB;            // [SCB]

    hipMemsetAsync(acc8, 0, 8 * sizeof(float), stream);
    hipMemsetAsync(cnt,  0, NND * sizeof(int), stream);
    hipMemsetAsync(cnt2, 0, NND * sizeof(int), stream);
    hipMemsetAsync(g,    0, NG * 128 * sizeof(float), stream);

    k_mean<<<256, 256, 0, stream>>>(ef, acc8);
    k_prep<<<1, 128, 0, stream>>>(acc8, We[0], ae[0], We[1], ae[1], We[2], ae[2], M, sc);

    k_hist<<<(NET + 255) / 256, 256, 0, stream>>>(ei, cnt);
    k_scan1<<<SCB, 256, 0, stream>>>(cnt, bsum);
    k_scan2<<<1, 256, 0, stream>>>(bsum, boff, rs);
    k_scan3<<<SCB, 256, 0, stream>>>(cnt, boff, rs);
    k_scatter<<<(NET + 255) / 256, 256, 0, stream>>>(ei, rs, cnt2, srcarr, slotof);

    const float* xin = x;
    for (int l = 0; l < 3; l++){
        int Fin = (l == 0) ? 30 : 128;
        k_gemm<<<(NND + 31) / 32, 256, 0, stream>>>(xin, W[l], as_[l], ad_[l],
                                                    Hb, als, ald, Fin);
        k_weight<<<(NE + NND + 255) / 256, 256, 0, stream>>>(
            ei, ef, (const float4*)als, (const float4*)ald,
            M + l * 32, sc + l * 4, rs, slotof, (float4*)wSf);
        k_gather<<<NND / 4, 256, 0, stream>>>(srcarr, rs, wSf, (const float2*)Hb, b_[l], Bx);
        xin = Bx;
    }

    k_pool<<<(NND + 31) / 32, 128, 0, stream>>>(Bx, batch, g);
    k_mlp<<<NG / 4, 128, 0, stream>>>(g, lw1, lb1, lw2, lb2, lw3, lb3, (float*)d_out);
}

// Round 6
// 593.731 us; speedup vs baseline: 4.2250x; 1.0003x over previous
//
#include <hip/hip_runtime.h>

#define NND 50000
#define NE  800000
#define NET 850000   // NE + NND self-loops
#define NG  2048
#define KT  32
#define SCB 196      // scan blocks = ceil(NND/256)

__device__ __forceinline__ float frelu(float v){ return v > 0.f ? v : 0.f; }

// ---------------- mean of edge_features: block-reduce, 8 atomics/block ----------
__global__ __launch_bounds__(256) void k_mean(const float* __restrict__ ef,
                                              float* __restrict__ acc8){
    __shared__ float red[256];
    int tid = threadIdx.x;
    int i0 = blockIdx.x * 256 + tid;
    int stride = gridDim.x * 256;
    float s = 0.f;
    for (int i = i0; i < NE * 8; i += stride) s += ef[i];
    red[tid] = s;
    __syncthreads();
    for (int off = 128; off >= 8; off >>= 1){
        if (tid < off) red[tid] += red[tid + off];
        __syncthreads();
    }
    if (tid < 8) atomicAdd(&acc8[tid], red[tid]);
}

// ---------------- M[3][8][4] and self-loop al_e constants sc[3][4] ---------------
__global__ void k_prep(const float* __restrict__ acc8,
                       const float* __restrict__ We1, const float* __restrict__ ae1,
                       const float* __restrict__ We2, const float* __restrict__ ae2,
                       const float* __restrict__ We3, const float* __restrict__ ae3,
                       float* __restrict__ M, float* __restrict__ sc){
    __shared__ float me[8];
    __shared__ float Ms[96];
    int t = threadIdx.x;
    if (t < 8) me[t] = acc8[t] * (1.0f / NE);
    if (t < 96){
        int l = t >> 5, f = (t >> 2) & 7, h = t & 3;
        const float* We = (l == 0) ? We1 : ((l == 1) ? We2 : We3);
        const float* ae = (l == 0) ? ae1 : ((l == 1) ? ae2 : ae3);
        float s = 0.f;
        for (int c = 0; c < 32; c++) s += We[f * 128 + h * 32 + c] * ae[h * 32 + c];
        M[t] = s; Ms[t] = s;
    }
    __syncthreads();
    if (t < 12){
        int l = t >> 2, h = t & 3;
        float s = 0.f;
        for (int f = 0; f < 8; f++) s += me[f] * Ms[l * 32 + f * 4 + h];
        sc[t] = s;
    }
}

// ------------- tiled GEMM: h = x @ W, fused als/ald epilogue --------------------
__global__ __launch_bounds__(256) void k_gemm(
        const float* __restrict__ x, const float* __restrict__ W,
        const float* __restrict__ asrc, const float* __restrict__ adst,
        float* __restrict__ h, float* __restrict__ als, float* __restrict__ ald,
        int Fin){
    __shared__ float Ws[KT * 128];       // [k][col]
    __shared__ float xst[KT * 36];       // [k][row], stride 36
    int t  = threadIdx.x;
    int cg = t & 31;
    int rg = t >> 5;
    int r0 = blockIdx.x * 32;
    float acc[4][4] = {{0.f}};
    int nch = (Fin + KT - 1) / KT;
    for (int ch = 0; ch < nch; ch++){
        int k0 = ch * KT;
        {
            const float4* Wv = (const float4*)(W + k0 * 128);
            float4* Wsv = (float4*)Ws;
            int lim = (Fin - k0 >= KT ? KT : Fin - k0) * 32;
            for (int i = t; i < KT * 32; i += 256)
                Wsv[i] = (i < lim) ? Wv[i] : make_float4(0.f, 0.f, 0.f, 0.f);
        }
        for (int i = t; i < 32 * KT; i += 256){
            int r = i >> 5, kk = i & 31;
            int gr = r0 + r;
            float v = 0.f;
            if (gr < NND && (k0 + kk) < Fin) v = x[gr * Fin + k0 + kk];
            xst[kk * 36 + r] = v;
        }
        __syncthreads();
        #pragma unroll 8
        for (int k = 0; k < KT; k++){
            float4 xv = *(const float4*)&xst[k * 36 + rg * 4];
            float4 wv = *(const float4*)&Ws[k * 128 + cg * 4];
            acc[0][0] += xv.x * wv.x; acc[0][1] += xv.x * wv.y;
            acc[0][2] += xv.x * wv.z; acc[0][3] += xv.x * wv.w;
            acc[1][0] += xv.y * wv.x; acc[1][1] += xv.y * wv.y;
            acc[1][2] += xv.y * wv.z; acc[1][3] += xv.y * wv.w;
            acc[2][0] += xv.z * wv.x; acc[2][1] += xv.z * wv.y;
            acc[2][2] += xv.z * wv.z; acc[2][3] += xv.z * wv.w;
            acc[3][0] += xv.w * wv.x; acc[3][1] += xv.w * wv.y;
            acc[3][2] += xv.w * wv.z; acc[3][3] += xv.w * wv.w;
        }
        __syncthreads();
    }
    float4 av = *(const float4*)&asrc[cg * 4];
    float4 dv = *(const float4*)&adst[cg * 4];
    int head = cg >> 3;
    bool leader = ((cg & 7) == 0);
    #pragma unroll
    for (int r = 0; r < 4; r++){
        int gr = r0 + rg * 4 + r;
        float4 o = make_float4(acc[r][0], acc[r][1], acc[r][2], acc[r][3]);
        if (gr < NND) *(float4*)&h[gr * 128 + cg * 4] = o;
        float sv = o.x * av.x + o.y * av.y + o.z * av.z + o.w * av.w;
        float sd = o.x * dv.x + o.y * dv.y + o.z * dv.z + o.w * dv.w;
        sv += __shfl_down(sv, 4, 64); sd += __shfl_down(sd, 4, 64);
        sv += __shfl_down(sv, 2, 64); sd += __shfl_down(sd, 2, 64);
        sv += __shfl_down(sv, 1, 64); sd += __shfl_down(sd, 1, 64);
        if (leader && gr < NND){
            als[gr * 4 + head] = sv;
            ald[gr * 4 + head] = sd;
        }
    }
}

// ---------------- CSR build: histogram of dst (incl. self-loops) ----------------
__global__ void k_hist(const int* __restrict__ ei, int* __restrict__ cnt){
    int e = blockIdx.x * 256 + threadIdx.x;
    if (e >= NET) return;
    int d = (e < NE) ? ei[NE + e] : (e - NE);
    atomicAdd(&cnt[d], 1);
}

// ---------------- scan phase 1: per-block sums ----------------------------------
__global__ __launch_bounds__(256) void k_scan1(const int* __restrict__ cnt,
                                               int* __restrict__ bsum){
    __shared__ int red[256];
    int t = threadIdx.x;
    int idx = blockIdx.x * 256 + t;
    red[t] = (idx < NND) ? cnt[idx] : 0;
    __syncthreads();
    for (int off = 128; off > 0; off >>= 1){
        if (t < off) red[t] += red[t + off];
        __syncthreads();
    }
    if (t == 0) bsum[blockIdx.x] = red[0];
}

// ---------------- scan phase 2: scan the 196 block sums (1 tiny block) ----------
__global__ __launch_bounds__(256) void k_scan2(const int* __restrict__ bsum,
                                               int* __restrict__ boff,
                                               int* __restrict__ rs){
    __shared__ int ls[256];
    int t = threadIdx.x;
    int v = (t < SCB) ? bsum[t] : 0;
    ls[t] = v;
    __syncthreads();
    for (int off = 1; off < 256; off <<= 1){
        int u = (t >= off) ? ls[t - off] : 0;
        __syncthreads();
        ls[t] += u;
        __syncthreads();
    }
    if (t < SCB) boff[t] = ls[t] - bsum[t];
    if (t == 0)  rs[NND] = ls[255];
}

// ---------------- scan phase 3: per-block exclusive scan + offset ---------------
__global__ __launch_bounds__(256) void k_scan3(const int* __restrict__ cnt,
                                               const int* __restrict__ boff,
                                               int* __restrict__ rs){
    __shared__ int ls[256];
    int t = threadIdx.x;
    int idx = blockIdx.x * 256 + t;
    int v = (idx < NND) ? cnt[idx] : 0;
    ls[t] = v;
    __syncthreads();
    for (int off = 1; off < 256; off <<= 1){
        int u = (t >= off) ? ls[t - off] : 0;
        __syncthreads();
        ls[t] += u;
        __syncthreads();
    }
    if (idx < NND) rs[idx] = boff[blockIdx.x] + ls[t] - v;
}

// ---------------- CSR build: scatter. Slot 0 of each segment = self-loop --------
__global__ void k_scatter(const int* __restrict__ ei, const int* __restrict__ rs,
                          int* __restrict__ cnt2, int* __restrict__ srcarr,
                          int* __restrict__ slotof){
    int e = blockIdx.x * 256 + threadIdx.x;
    if (e >= NET) return;
    if (e < NE){
        int s = ei[e], d = ei[NE + e];
        int pos = atomicAdd(&cnt2[d], 1) + 1;
        int slot = rs[d] + pos;
        srcarr[slot] = s;
        slotof[e] = slot;
    } else {
        int n = e - NE;
        srcarr[rs[n]] = n;
    }
}

// ---------------- per-edge attention weights -> CSR slot order ------------------
__global__ __launch_bounds__(256) void k_weight(
        const int* __restrict__ ei, const float* __restrict__ ef,
        const float4* __restrict__ als4, const float4* __restrict__ ald4,
        const float* __restrict__ Mg, const float* __restrict__ sc4g,
        const int* __restrict__ rs, const int* __restrict__ slotof,
        float4* __restrict__ wS){
    __shared__ float Ms[32];
    __shared__ float Scs[4];
    int t = threadIdx.x;
    if (t < 32) Ms[t] = Mg[t];
    if (t < 4)  Scs[t] = sc4g[t];
    __syncthreads();
    int e = blockIdx.x * 256 + t;
    if (e < NE){
        int s = ei[e], d = ei[NE + e];
        const float4* efp = (const float4*)ef;
        float4 u = efp[e * 2], v = efp[e * 2 + 1];
        float4 A = als4[s], D = ald4[d];
        float4 w;
        float* wp = &w.x;
        const float* Ap = &A.x; const float* Dp = &D.x;
        #pragma unroll
        for (int h = 0; h < 4; h++){
            float ae = u.x * Ms[0 + h]  + u.y * Ms[4 + h]
                     + u.z * Ms[8 + h]  + u.w * Ms[12 + h]
                     + v.x * Ms[16 + h] + v.y * Ms[20 + h]
                     + v.z * Ms[24 + h] + v.w * Ms[28 + h];
            float a = Ap[h] + Dp[h] + ae;
            a = a > 0.f ? a : 0.2f * a;
            wp[h] = __expf(a);
        }
        wS[slotof[e]] = w;
    } else if (e < NE + NND){
        int n = e - NE;
        float4 A = als4[n], D = ald4[n];
        float4 w;
        float* wp = &w.x;
        const float* Ap = &A.x; const float* Dp = &D.x;
        #pragma unroll
        for (int h = 0; h < 4; h++){
            float a = Ap[h] + Dp[h] + Scs[h];
            a = a > 0.f ? a : 0.2f * a;
            wp[h] = __expf(a);
        }
        wS[rs[n]] = w;
    }
}

// ---------------- gather: one wave per node, 8-deep pipeline, masked tail -------
__global__ __launch_bounds__(256) void k_gather(
        const int* __restrict__ srcarr, const int* __restrict__ rs,
        const float* __restrict__ wS,
        const float2* __restrict__ H2,
        const float* __restrict__ b, float* __restrict__ out){
    int wid  = threadIdx.x >> 6;
    int lane = threadIdx.x & 63;
    int n = blockIdx.x * 4 + wid;
    int start = rs[n], end = rs[n + 1];
    int cnt = end - start;
    int mh = lane >> 4;
    float ax = 0.f, ay = 0.f, accw = 0.f;

    int s[8]; float w[8];
    int k = 0;
    if (cnt >= 8){
        #pragma unroll
        for (int j = 0; j < 8; j++){
            int i = start + j;
            s[j] = srcarr[i];
            w[j] = wS[i * 4 + mh];
        }
    }
    while (k + 8 <= cnt){
        int cs[8]; float cw[8];
        #pragma unroll
        for (int j = 0; j < 8; j++){ cs[j] = s[j]; cw[j] = w[j]; }
        k += 8;
        if (k + 8 <= cnt){
            #pragma unroll
            for (int j = 0; j < 8; j++){
                int i = start + k + j;
                s[j] = srcarr[i];
                w[j] = wS[i * 4 + mh];
            }
        }
        float2 hv[8];
        #pragma unroll
        for (int j = 0; j < 8; j++) hv[j] = H2[cs[j] * 64 + lane];
        #pragma unroll
        for (int j = 0; j < 8; j++){
            ax += cw[j] * hv[j].x;
            ay += cw[j] * hv[j].y;
            accw += cw[j];
        }
    }
    int rem = cnt - k;
    if (rem > 0){
        // one masked 8-wide pass: invalid j clamps to slot `start` (valid, L1-hot)
        int ts[8]; float tw[8];
        #pragma unroll
        for (int j = 0; j < 8; j++){
            bool v = j < rem;
            int i = v ? (start + k + j) : start;
            ts[j] = srcarr[i];
            tw[j] = v ? wS[i * 4 + mh] : 0.f;
        }
        float2 hv[8];
        #pragma unroll
        for (int j = 0; j < 8; j++) hv[j] = H2[ts[j] * 64 + lane];
        #pragma unroll
        for (int j = 0; j < 8; j++){
            ax += tw[j] * hv[j].x;
            ay += tw[j] * hv[j].y;
            accw += tw[j];
        }
    }
    float inv = 1.f / (accw + 1e-16f);
    int c0 = 2 * lane;
    float2 o;
    o.x = frelu(ax * inv + b[c0]);
    o.y = frelu(ay * inv + b[c0 + 1]);
    ((float2*)out)[n * 64 + lane] = o;
}

// ---------------- global add pool: run-length compress sorted batch -------------
__global__ __launch_bounds__(128) void k_pool(const float* __restrict__ y,
                                              const int* __restrict__ batch,
                                              float* __restrict__ g){
    int c = threadIdx.x;
    int n0 = blockIdx.x * 32;
    if (n0 >= NND) return;
    int cur = batch[n0];
    float s = 0.f;
    for (int k = 0; k < 32; k++){
        int n = n0 + k;
        if (n >= NND) break;
        int bg = batch[n];
        if (bg != cur){
            atomicAdd(&g[cur * 128 + c], s);
            s = 0.f; cur = bg;
        }
        s += y[n * 128 + c];
    }
    atomicAdd(&g[cur * 128 + c], s);
}

// ---------------- MLP head: 128->32->32->1 --------------------------------------
__global__ void k_mlp(const float* __restrict__ g,
                      const float* __restrict__ lw1, const float* __restrict__ lb1,
                      const float* __restrict__ lw2, const float* __restrict__ lb2,
                      const float* __restrict__ lw3, const float* __restrict__ lb3,
                      float* __restrict__ out){
    __shared__ float t1[4][32];
    __shared__ float t2[4][32];
    int tid = threadIdx.x, sub = tid >> 5, j = tid & 31;
    int gi = blockIdx.x * 4 + sub;
    const float* gr = g + gi * 128;
    float s = lb1[j];
    for (int c = 0; c < 128; c++) s += gr[c] * lw1[c * 32 + j];
    t1[sub][j] = frelu(s);
    __syncthreads();
    float s2 = lb2[j];
    for (int k = 0; k < 32; k++) s2 += t1[sub][k] * lw2[k * 32 + j];
    t2[sub][j] = frelu(s2);
    __syncthreads();
    if (j == 0){
        float o = lb3[0];
        for (int k = 0; k < 32; k++) o += t2[sub][k] * lw3[k];
        out[gi] = frelu(o);
    }
}

extern "C" void kernel_launch(void* const* d_in, const int* in_sizes, int n_in,
                              void* d_out, int out_size, void* d_ws, size_t ws_size,
                              hipStream_t stream) {
    const float* x     = (const float*)d_in[0];
    const int*   ei    = (const int*)  d_in[1];
    const float* ef    = (const float*)d_in[2];
    const int*   batch = (const int*)  d_in[3];
    const float* W[3]   = {(const float*)d_in[4],  (const float*)d_in[10], (const float*)d_in[16]};
    const float* as_[3] = {(const float*)d_in[5],  (const float*)d_in[11], (const float*)d_in[17]};
    const float* ad_[3] = {(const float*)d_in[6],  (const float*)d_in[12], (const float*)d_in[18]};
    const float* We[3]  = {(const float*)d_in[7],  (const float*)d_in[13], (const float*)d_in[19]};
    const float* ae[3]  = {(const float*)d_in[8],  (const float*)d_in[14], (const float*)d_in[20]};
    const float* b_[3]  = {(const float*)d_in[9],  (const float*)d_in[15], (const float*)d_in[21]};
    const float* lw1 = (const float*)d_in[22]; const float* lb1 = (const float*)d_in[23];
    const float* lw2 = (const float*)d_in[24]; const float* lb2 = (const float*)d_in[25];
    const float* lw3 = (const float*)d_in[26]; const float* lb3 = (const float*)d_in[27];

    float* ws = (float*)d_ws;
    float* Bx   = ws;                      // layer in/out  [NND*128]
    float* Hb   = Bx + 6400000;            // h buffer      [NND*128]
    float* wSf  = Hb + 6400000;            // weights/slot  [NET*4]
    float* als  = wSf + 3400000;           // [NND*4]
    float* ald  = als + 200000;            // [NND*4]
    float* g    = ald + 200000;            // [NG*128]
    float* acc8 = g + 262144;              // [8]
    float* M    = acc8 + 8;                // [96]
    float* sc   = M + 96;                  // [12] + pad
    int*   srcarr = (int*)(sc + 16);       // [NET]
    int*   slotof = srcarr + NET;          // [NE]
    int*   rs     = slotof + NE;           // [NND+1] (+pad)
    int*   cnt    = rs + NND + 4;          // [NND]
    int*   cnt2   = cnt + NND;             // [NND]
    int*   bsum   = cnt2 + NND;            // [SCB]
    int*   boff   = bsum + SCB;            // [SCB]

    hipMemsetAsync(acc8, 0, 8 * sizeof(float), stream);
    hipMemsetAsync(cnt,  0, NND * sizeof(int), stream);
    hipMemsetAsync(cnt2, 0, NND * sizeof(int), stream);
    hipMemsetAsync(g,    0, NG * 128 * sizeof(float), stream);

    k_mean<<<256, 256, 0, stream>>>(ef, acc8);
    k_prep<<<1, 128, 0, stream>>>(acc8, We[0], ae[0], We[1], ae[1], We[2], ae[2], M, sc);

    k_hist<<<(NET + 255) / 256, 256, 0, stream>>>(ei, cnt);
    k_scan1<<<SCB, 256, 0, stream>>>(cnt, bsum);
    k_scan2<<<1, 256, 0, stream>>>(bsum, boff, rs);
    k_scan3<<<SCB, 256, 0, stream>>>(cnt, boff, rs);
    k_scatter<<<(NET + 255) / 256, 256, 0, stream>>>(ei, rs, cnt2, srcarr, slotof);

    const float* xin = x;
    for (int l = 0; l < 3; l++){
        int Fin = (l == 0) ? 30 : 128;
        k_gemm<<<(NND + 31) / 32, 256, 0, stream>>>(xin, W[l], as_[l], ad_[l],
                                                    Hb, als, ald, Fin);
        k_weight<<<(NE + NND + 255) / 256, 256, 0, stream>>>(
            ei, ef, (const float4*)als, (const float4*)ald,
            M + l * 32, sc + l * 4, rs, slotof, (float4*)wSf);
        k_gather<<<NND / 4, 256, 0, stream>>>(srcarr, rs, wSf, (const float2*)Hb, b_[l], Bx);
        xin = Bx;
    }

    k_pool<<<(NND + 31) / 32, 128, 0, stream>>>(Bx, batch, g);
    k_mlp<<<NG / 4, 128, 0, stream>>>(g, lw1, lb1, lw2, lb2, lw3, lb3, (float*)d_out);
}

// Round 7
// 509.668 us; speedup vs baseline: 4.9219x; 1.1649x over previous
//
#include <hip/hip_runtime.h>

#define NND 50000
#define NE  800000
#define NET 850000   // NE + NND self-loops
#define NG  2048
#define KT  32
#define SCB 196      // scan blocks = ceil(NND/256)

__device__ __forceinline__ float frelu(float v){ return v > 0.f ? v : 0.f; }

// round-to-nearest-even float -> bf16 bits
__device__ __forceinline__ unsigned short f2bf(float f){
    unsigned int u = __float_as_uint(f);
    u += 0x7FFFu + ((u >> 16) & 1u);
    return (unsigned short)(u >> 16);
}

// ---------------- mean of edge_features: block-reduce, 8 atomics/block ----------
__global__ __launch_bounds__(256) void k_mean(const float* __restrict__ ef,
                                              float* __restrict__ acc8){
    __shared__ float red[256];
    int tid = threadIdx.x;
    int i0 = blockIdx.x * 256 + tid;
    int stride = gridDim.x * 256;
    float s = 0.f;
    for (int i = i0; i < NE * 8; i += stride) s += ef[i];
    red[tid] = s;
    __syncthreads();
    for (int off = 128; off >= 8; off >>= 1){
        if (tid < off) red[tid] += red[tid + off];
        __syncthreads();
    }
    if (tid < 8) atomicAdd(&acc8[tid], red[tid]);
}

// ---------------- M[3][8][4] and self-loop al_e constants sc[3][4] ---------------
__global__ void k_prep(const float* __restrict__ acc8,
                       const float* __restrict__ We1, const float* __restrict__ ae1,
                       const float* __restrict__ We2, const float* __restrict__ ae2,
                       const float* __restrict__ We3, const float* __restrict__ ae3,
                       float* __restrict__ M, float* __restrict__ sc){
    __shared__ float me[8];
    __shared__ float Ms[96];
    int t = threadIdx.x;
    if (t < 8) me[t] = acc8[t] * (1.0f / NE);
    if (t < 96){
        int l = t >> 5, f = (t >> 2) & 7, h = t & 3;
        const float* We = (l == 0) ? We1 : ((l == 1) ? We2 : We3);
        const float* ae = (l == 0) ? ae1 : ((l == 1) ? ae2 : ae3);
        float s = 0.f;
        for (int c = 0; c < 32; c++) s += We[f * 128 + h * 32 + c] * ae[h * 32 + c];
        M[t] = s; Ms[t] = s;
    }
    __syncthreads();
    if (t < 12){
        int l = t >> 2, h = t & 3;
        float s = 0.f;
        for (int f = 0; f < 8; f++) s += me[f] * Ms[l * 32 + f * 4 + h];
        sc[t] = s;
    }
}

// ------------- tiled GEMM: h = x @ W (bf16 h out), fused als/ald epilogue -------
__global__ __launch_bounds__(256) void k_gemm(
        const float* __restrict__ x, const float* __restrict__ W,
        const float* __restrict__ asrc, const float* __restrict__ adst,
        unsigned short* __restrict__ h, float* __restrict__ als,
        float* __restrict__ ald, int Fin){
    __shared__ float Ws[KT * 128];       // [k][col]
    __shared__ float xst[KT * 36];       // [k][row], stride 36
    int t  = threadIdx.x;
    int cg = t & 31;
    int rg = t >> 5;
    int r0 = blockIdx.x * 32;
    float acc[4][4] = {{0.f}};
    int nch = (Fin + KT - 1) / KT;
    for (int ch = 0; ch < nch; ch++){
        int k0 = ch * KT;
        {
            const float4* Wv = (const float4*)(W + k0 * 128);
            float4* Wsv = (float4*)Ws;
            int lim = (Fin - k0 >= KT ? KT : Fin - k0) * 32;
            for (int i = t; i < KT * 32; i += 256)
                Wsv[i] = (i < lim) ? Wv[i] : make_float4(0.f, 0.f, 0.f, 0.f);
        }
        for (int i = t; i < 32 * KT; i += 256){
            int r = i >> 5, kk = i & 31;
            int gr = r0 + r;
            float v = 0.f;
            if (gr < NND && (k0 + kk) < Fin) v = x[gr * Fin + k0 + kk];
            xst[kk * 36 + r] = v;
        }
        __syncthreads();
        #pragma unroll 8
        for (int k = 0; k < KT; k++){
            float4 xv = *(const float4*)&xst[k * 36 + rg * 4];
            float4 wv = *(const float4*)&Ws[k * 128 + cg * 4];
            acc[0][0] += xv.x * wv.x; acc[0][1] += xv.x * wv.y;
            acc[0][2] += xv.x * wv.z; acc[0][3] += xv.x * wv.w;
            acc[1][0] += xv.y * wv.x; acc[1][1] += xv.y * wv.y;
            acc[1][2] += xv.y * wv.z; acc[1][3] += xv.y * wv.w;
            acc[2][0] += xv.z * wv.x; acc[2][1] += xv.z * wv.y;
            acc[2][2] += xv.z * wv.z; acc[2][3] += xv.z * wv.w;
            acc[3][0] += xv.w * wv.x; acc[3][1] += xv.w * wv.y;
            acc[3][2] += xv.w * wv.z; acc[3][3] += xv.w * wv.w;
        }
        __syncthreads();
    }
    float4 av = *(const float4*)&asrc[cg * 4];
    float4 dv = *(const float4*)&adst[cg * 4];
    int head = cg >> 3;
    bool leader = ((cg & 7) == 0);
    #pragma unroll
    for (int r = 0; r < 4; r++){
        int gr = r0 + rg * 4 + r;
        float4 o = make_float4(acc[r][0], acc[r][1], acc[r][2], acc[r][3]);
        if (gr < NND){
            ushort4 p;
            p.x = f2bf(o.x); p.y = f2bf(o.y); p.z = f2bf(o.z); p.w = f2bf(o.w);
            *(ushort4*)&h[gr * 128 + cg * 4] = p;
        }
        float sv = o.x * av.x + o.y * av.y + o.z * av.z + o.w * av.w;
        float sd = o.x * dv.x + o.y * dv.y + o.z * dv.z + o.w * dv.w;
        sv += __shfl_down(sv, 4, 64); sd += __shfl_down(sd, 4, 64);
        sv += __shfl_down(sv, 2, 64); sd += __shfl_down(sd, 2, 64);
        sv += __shfl_down(sv, 1, 64); sd += __shfl_down(sd, 1, 64);
        if (leader && gr < NND){
            als[gr * 4 + head] = sv;
            ald[gr * 4 + head] = sd;
        }
    }
}

// ---------------- CSR build: histogram of dst (incl. self-loops) ----------------
__global__ void k_hist(const int* __restrict__ ei, int* __restrict__ cnt){
    int e = blockIdx.x * 256 + threadIdx.x;
    if (e >= NET) return;
    int d = (e < NE) ? ei[NE + e] : (e - NE);
    atomicAdd(&cnt[d], 1);
}

// ---------------- scan phase 1: per-block sums ----------------------------------
__global__ __launch_bounds__(256) void k_scan1(const int* __restrict__ cnt,
                                               int* __restrict__ bsum){
    __shared__ int red[256];
    int t = threadIdx.x;
    int idx = blockIdx.x * 256 + t;
    red[t] = (idx < NND) ? cnt[idx] : 0;
    __syncthreads();
    for (int off = 128; off > 0; off >>= 1){
        if (t < off) red[t] += red[t + off];
        __syncthreads();
    }
    if (t == 0) bsum[blockIdx.x] = red[0];
}

// ---------------- scan phase 2: scan the 196 block sums -------------------------
__global__ __launch_bounds__(256) void k_scan2(const int* __restrict__ bsum,
                                               int* __restrict__ boff,
                                               int* __restrict__ rs){
    __shared__ int ls[256];
    int t = threadIdx.x;
    int v = (t < SCB) ? bsum[t] : 0;
    ls[t] = v;
    __syncthreads();
    for (int off = 1; off < 256; off <<= 1){
        int u = (t >= off) ? ls[t - off] : 0;
        __syncthreads();
        ls[t] += u;
        __syncthreads();
    }
    if (t < SCB) boff[t] = ls[t] - bsum[t];
    if (t == 0)  rs[NND] = ls[255];
}

// ---------------- scan phase 3: per-block exclusive scan + offset ---------------
__global__ __launch_bounds__(256) void k_scan3(const int* __restrict__ cnt,
                                               const int* __restrict__ boff,
                                               int* __restrict__ rs){
    __shared__ int ls[256];
    int t = threadIdx.x;
    int idx = blockIdx.x * 256 + t;
    int v = (idx < NND) ? cnt[idx] : 0;
    ls[t] = v;
    __syncthreads();
    for (int off = 1; off < 256; off <<= 1){
        int u = (t >= off) ? ls[t - off] : 0;
        __syncthreads();
        ls[t] += u;
        __syncthreads();
    }
    if (idx < NND) rs[idx] = boff[blockIdx.x] + ls[t] - v;
}

// ---------------- CSR build: scatter. Slot 0 of each segment = self-loop --------
__global__ void k_scatter(const int* __restrict__ ei, const int* __restrict__ rs,
                          int* __restrict__ cnt2, int* __restrict__ srcarr,
                          int* __restrict__ slotof){
    int e = blockIdx.x * 256 + threadIdx.x;
    if (e >= NET) return;
    if (e < NE){
        int s = ei[e], d = ei[NE + e];
        int pos = atomicAdd(&cnt2[d], 1) + 1;
        int slot = rs[d] + pos;
        srcarr[slot] = s;
        slotof[e] = slot;
    } else {
        int n = e - NE;
        srcarr[rs[n]] = n;
    }
}

// ---------------- per-edge attention weights -> CSR slot order ------------------
__global__ __launch_bounds__(256) void k_weight(
        const int* __restrict__ ei, const float* __restrict__ ef,
        const float4* __restrict__ als4, const float4* __restrict__ ald4,
        const float* __restrict__ Mg, const float* __restrict__ sc4g,
        const int* __restrict__ rs, const int* __restrict__ slotof,
        float4* __restrict__ wS){
    __shared__ float Ms[32];
    __shared__ float Scs[4];
    int t = threadIdx.x;
    if (t < 32) Ms[t] = Mg[t];
    if (t < 4)  Scs[t] = sc4g[t];
    __syncthreads();
    int e = blockIdx.x * 256 + t;
    if (e < NE){
        int s = ei[e], d = ei[NE + e];
        const float4* efp = (const float4*)ef;
        float4 u = efp[e * 2], v = efp[e * 2 + 1];
        float4 A = als4[s], D = ald4[d];
        float4 w;
        float* wp = &w.x;
        const float* Ap = &A.x; const float* Dp = &D.x;
        #pragma unroll
        for (int h = 0; h < 4; h++){
            float ae = u.x * Ms[0 + h]  + u.y * Ms[4 + h]
                     + u.z * Ms[8 + h]  + u.w * Ms[12 + h]
                     + v.x * Ms[16 + h] + v.y * Ms[20 + h]
                     + v.z * Ms[24 + h] + v.w * Ms[28 + h];
            float a = Ap[h] + Dp[h] + ae;
            a = a > 0.f ? a : 0.2f * a;
            wp[h] = __expf(a);
        }
        wS[slotof[e]] = w;
    } else if (e < NE + NND){
        int n = e - NE;
        float4 A = als4[n], D = ald4[n];
        float4 w;
        float* wp = &w.x;
        const float* Ap = &A.x; const float* Dp = &D.x;
        #pragma unroll
        for (int h = 0; h < 4; h++){
            float a = Ap[h] + Dp[h] + Scs[h];
            a = a > 0.f ? a : 0.2f * a;
            wp[h] = __expf(a);
        }
        wS[rs[n]] = w;
    }
}

// ---------------- gather: bf16 h rows, one wave/node, 8-deep pipeline -----------
__global__ __launch_bounds__(256) void k_gather(
        const int* __restrict__ srcarr, const int* __restrict__ rs,
        const float* __restrict__ wS,
        const unsigned int* __restrict__ HU,    // bf16x2 rows [NND][64]
        const float* __restrict__ b, float* __restrict__ out){
    int wid  = threadIdx.x >> 6;
    int lane = threadIdx.x & 63;
    int n = blockIdx.x * 4 + wid;
    int start = rs[n], end = rs[n + 1];
    int cnt = end - start;
    int mh = lane >> 4;
    float ax = 0.f, ay = 0.f, accw = 0.f;

    int s[8]; float w[8];
    int k = 0;
    if (cnt >= 8){
        #pragma unroll
        for (int j = 0; j < 8; j++){
            int i = start + j;
            s[j] = srcarr[i];
            w[j] = wS[i * 4 + mh];
        }
    }
    while (k + 8 <= cnt){
        int cs[8]; float cw[8];
        #pragma unroll
        for (int j = 0; j < 8; j++){ cs[j] = s[j]; cw[j] = w[j]; }
        k += 8;
        if (k + 8 <= cnt){
            #pragma unroll
            for (int j = 0; j < 8; j++){
                int i = start + k + j;
                s[j] = srcarr[i];
                w[j] = wS[i * 4 + mh];
            }
        }
        unsigned int hv[8];
        #pragma unroll
        for (int j = 0; j < 8; j++) hv[j] = HU[cs[j] * 64 + lane];
        #pragma unroll
        for (int j = 0; j < 8; j++){
            float lo = __uint_as_float(hv[j] << 16);
            float hi = __uint_as_float(hv[j] & 0xFFFF0000u);
            ax += cw[j] * lo;
            ay += cw[j] * hi;
            accw += cw[j];
        }
    }
    int rem = cnt - k;
    if (rem > 0){
        int ts[8]; float tw[8];
        #pragma unroll
        for (int j = 0; j < 8; j++){
            bool v = j < rem;
            int i = v ? (start + k + j) : start;
            ts[j] = srcarr[i];
            tw[j] = v ? wS[i * 4 + mh] : 0.f;
        }
        unsigned int hv[8];
        #pragma unroll
        for (int j = 0; j < 8; j++) hv[j] = HU[ts[j] * 64 + lane];
        #pragma unroll
        for (int j = 0; j < 8; j++){
            float lo = __uint_as_float(hv[j] << 16);
            float hi = __uint_as_float(hv[j] & 0xFFFF0000u);
            ax += tw[j] * lo;
            ay += tw[j] * hi;
            accw += tw[j];
        }
    }
    float inv = 1.f / (accw + 1e-16f);
    int c0 = 2 * lane;
    float2 o;
    o.x = frelu(ax * inv + b[c0]);
    o.y = frelu(ay * inv + b[c0 + 1]);
    ((float2*)out)[n * 64 + lane] = o;
}

// ---------------- global add pool: run-length compress sorted batch -------------
__global__ __launch_bounds__(128) void k_pool(const float* __restrict__ y,
                                              const int* __restrict__ batch,
                                              float* __restrict__ g){
    int c = threadIdx.x;
    int n0 = blockIdx.x * 32;
    if (n0 >= NND) return;
    int cur = batch[n0];
    float s = 0.f;
    for (int k = 0; k < 32; k++){
        int n = n0 + k;
        if (n >= NND) break;
        int bg = batch[n];
        if (bg != cur){
            atomicAdd(&g[cur * 128 + c], s);
            s = 0.f; cur = bg;
        }
        s += y[n * 128 + c];
    }
    atomicAdd(&g[cur * 128 + c], s);
}

// ---------------- MLP head: 128->32->32->1 --------------------------------------
__global__ void k_mlp(const float* __restrict__ g,
                      const float* __restrict__ lw1, const float* __restrict__ lb1,
                      const float* __restrict__ lw2, const float* __restrict__ lb2,
                      const float* __restrict__ lw3, const float* __restrict__ lb3,
                      float* __restrict__ out){
    __shared__ float t1[4][32];
    __shared__ float t2[4][32];
    int tid = threadIdx.x, sub = tid >> 5, j = tid & 31;
    int gi = blockIdx.x * 4 + sub;
    const float* gr = g + gi * 128;
    float s = lb1[j];
    for (int c = 0; c < 128; c++) s += gr[c] * lw1[c * 32 + j];
    t1[sub][j] = frelu(s);
    __syncthreads();
    float s2 = lb2[j];
    for (int k = 0; k < 32; k++) s2 += t1[sub][k] * lw2[k * 32 + j];
    t2[sub][j] = frelu(s2);
    __syncthreads();
    if (j == 0){
        float o = lb3[0];
        for (int k = 0; k < 32; k++) o += t2[sub][k] * lw3[k];
        out[gi] = frelu(o);
    }
}

extern "C" void kernel_launch(void* const* d_in, const int* in_sizes, int n_in,
                              void* d_out, int out_size, void* d_ws, size_t ws_size,
                              hipStream_t stream) {
    const float* x     = (const float*)d_in[0];
    const int*   ei    = (const int*)  d_in[1];
    const float* ef    = (const float*)d_in[2];
    const int*   batch = (const int*)  d_in[3];
    const float* W[3]   = {(const float*)d_in[4],  (const float*)d_in[10], (const float*)d_in[16]};
    const float* as_[3] = {(const float*)d_in[5],  (const float*)d_in[11], (const float*)d_in[17]};
    const float* ad_[3] = {(const float*)d_in[6],  (const float*)d_in[12], (const float*)d_in[18]};
    const float* We[3]  = {(const float*)d_in[7],  (const float*)d_in[13], (const float*)d_in[19]};
    const float* ae[3]  = {(const float*)d_in[8],  (const float*)d_in[14], (const float*)d_in[20]};
    const float* b_[3]  = {(const float*)d_in[9],  (const float*)d_in[15], (const float*)d_in[21]};
    const float* lw1 = (const float*)d_in[22]; const float* lb1 = (const float*)d_in[23];
    const float* lw2 = (const float*)d_in[24]; const float* lb2 = (const float*)d_in[25];
    const float* lw3 = (const float*)d_in[26]; const float* lb3 = (const float*)d_in[27];

    float* ws = (float*)d_ws;
    float* Bx   = ws;                      // layer in/out  [NND*128] fp32
    float* Hbf  = Bx + 6400000;            // h buffer bf16 [NND*128] (uses half)
    float* wSf  = Hbf + 6400000;           // weights/slot  [NET*4]
    float* als  = wSf + 3400000;           // [NND*4]
    float* ald  = als + 200000;            // [NND*4]
    float* g    = ald + 200000;            // [NG*128]
    float* acc8 = g + 262144;              // [8]
    float* M    = acc8 + 8;                // [96]
    float* sc   = M + 96;                  // [12] + pad
    int*   srcarr = (int*)(sc + 16);       // [NET]
    int*   slotof = srcarr + NET;          // [NE]
    int*   rs     = slotof + NE;           // [NND+1] (+pad)
    int*   cnt    = rs + NND + 4;          // [NND]
    int*   cnt2   = cnt + NND;             // [NND]
    int*   bsum   = cnt2 + NND;            // [SCB]
    int*   boff   = bsum + SCB;            // [SCB]

    unsigned short* Hb = (unsigned short*)Hbf;

    hipMemsetAsync(acc8, 0, 8 * sizeof(float), stream);
    hipMemsetAsync(cnt,  0, NND * sizeof(int), stream);
    hipMemsetAsync(cnt2, 0, NND * sizeof(int), stream);
    hipMemsetAsync(g,    0, NG * 128 * sizeof(float), stream);

    k_mean<<<256, 256, 0, stream>>>(ef, acc8);
    k_prep<<<1, 128, 0, stream>>>(acc8, We[0], ae[0], We[1], ae[1], We[2], ae[2], M, sc);

    k_hist<<<(NET + 255) / 256, 256, 0, stream>>>(ei, cnt);
    k_scan1<<<SCB, 256, 0, stream>>>(cnt, bsum);
    k_scan2<<<1, 256, 0, stream>>>(bsum, boff, rs);
    k_scan3<<<SCB, 256, 0, stream>>>(cnt, boff, rs);
    k_scatter<<<(NET + 255) / 256, 256, 0, stream>>>(ei, rs, cnt2, srcarr, slotof);

    const float* xin = x;
    for (int l = 0; l < 3; l++){
        int Fin = (l == 0) ? 30 : 128;
        k_gemm<<<(NND + 31) / 32, 256, 0, stream>>>(xin, W[l], as_[l], ad_[l],
                                                    Hb, als, ald, Fin);
        k_weight<<<(NE + NND + 255) / 256, 256, 0, stream>>>(
            ei, ef, (const float4*)als, (const float4*)ald,
            M + l * 32, sc + l * 4, rs, slotof, (float4*)wSf);
        k_gather<<<NND / 4, 256, 0, stream>>>(srcarr, rs, wSf,
                                              (const unsigned int*)Hb, b_[l], Bx);
        xin = Bx;
    }

    k_pool<<<(NND + 31) / 32, 128, 0, stream>>>(Bx, batch, g);
    k_mlp<<<NG / 4, 128, 0, stream>>>(g, lw1, lb1, lw2, lb2, lw3, lb3, (float*)d_out);
}

// Round 8
// 471.734 us; speedup vs baseline: 5.3177x; 1.0804x over previous
//
#include <hip/hip_runtime.h>

#define NND 50000
#define NE  800000
#define NET 850000   // NE + NND self-loops
#define NG  2048
#define KT  32
#define SCB 196      // scan blocks = ceil(NND/256)

__device__ __forceinline__ float frelu(float v){ return v > 0.f ? v : 0.f; }

// round-to-nearest-even float -> bf16 bits
__device__ __forceinline__ unsigned short f2bf(float f){
    unsigned int u = __float_as_uint(f);
    u += 0x7FFFu + ((u >> 16) & 1u);
    return (unsigned short)(u >> 16);
}

// ---------------- mean of edge_features: block-reduce, 8 atomics/block ----------
__global__ __launch_bounds__(256) void k_mean(const float* __restrict__ ef,
                                              float* __restrict__ acc8){
    __shared__ float red[256];
    int tid = threadIdx.x;
    int i0 = blockIdx.x * 256 + tid;
    int stride = gridDim.x * 256;
    float s = 0.f;
    for (int i = i0; i < NE * 8; i += stride) s += ef[i];
    red[tid] = s;
    __syncthreads();
    for (int off = 128; off >= 8; off >>= 1){
        if (tid < off) red[tid] += red[tid + off];
        __syncthreads();
    }
    if (tid < 8) atomicAdd(&acc8[tid], red[tid]);
}

// ---------------- M[3][8][4] and self-loop al_e constants sc[3][4] ---------------
__global__ void k_prep(const float* __restrict__ acc8,
                       const float* __restrict__ We1, const float* __restrict__ ae1,
                       const float* __restrict__ We2, const float* __restrict__ ae2,
                       const float* __restrict__ We3, const float* __restrict__ ae3,
                       float* __restrict__ M, float* __restrict__ sc){
    __shared__ float me[8];
    __shared__ float Ms[96];
    int t = threadIdx.x;
    if (t < 8) me[t] = acc8[t] * (1.0f / NE);
    if (t < 96){
        int l = t >> 5, f = (t >> 2) & 7, h = t & 3;
        const float* We = (l == 0) ? We1 : ((l == 1) ? We2 : We3);
        const float* ae = (l == 0) ? ae1 : ((l == 1) ? ae2 : ae3);
        float s = 0.f;
        for (int c = 0; c < 32; c++) s += We[f * 128 + h * 32 + c] * ae[h * 32 + c];
        M[t] = s; Ms[t] = s;
    }
    __syncthreads();
    if (t < 12){
        int l = t >> 2, h = t & 3;
        float s = 0.f;
        for (int f = 0; f < 8; f++) s += me[f] * Ms[l * 32 + f * 4 + h];
        sc[t] = s;
    }
}

// ------------- tiled GEMM: h = x @ W (bf16 h out), fused als/ald epilogue -------
__global__ __launch_bounds__(256) void k_gemm(
        const float* __restrict__ x, const float* __restrict__ W,
        const float* __restrict__ asrc, const float* __restrict__ adst,
        unsigned short* __restrict__ h, float* __restrict__ als,
        float* __restrict__ ald, int Fin){
    __shared__ float Ws[KT * 128];       // [k][col]
    __shared__ float xst[KT * 36];       // [k][row], stride 36
    int t  = threadIdx.x;
    int cg = t & 31;
    int rg = t >> 5;
    int r0 = blockIdx.x * 32;
    float acc[4][4] = {{0.f}};
    int nch = (Fin + KT - 1) / KT;
    for (int ch = 0; ch < nch; ch++){
        int k0 = ch * KT;
        {
            const float4* Wv = (const float4*)(W + k0 * 128);
            float4* Wsv = (float4*)Ws;
            int lim = (Fin - k0 >= KT ? KT : Fin - k0) * 32;
            for (int i = t; i < KT * 32; i += 256)
                Wsv[i] = (i < lim) ? Wv[i] : make_float4(0.f, 0.f, 0.f, 0.f);
        }
        for (int i = t; i < 32 * KT; i += 256){
            int r = i >> 5, kk = i & 31;
            int gr = r0 + r;
            float v = 0.f;
            if (gr < NND && (k0 + kk) < Fin) v = x[gr * Fin + k0 + kk];
            xst[kk * 36 + r] = v;
        }
        __syncthreads();
        #pragma unroll 8
        for (int k = 0; k < KT; k++){
            float4 xv = *(const float4*)&xst[k * 36 + rg * 4];
            float4 wv = *(const float4*)&Ws[k * 128 + cg * 4];
            acc[0][0] += xv.x * wv.x; acc[0][1] += xv.x * wv.y;
            acc[0][2] += xv.x * wv.z; acc[0][3] += xv.x * wv.w;
            acc[1][0] += xv.y * wv.x; acc[1][1] += xv.y * wv.y;
            acc[1][2] += xv.y * wv.z; acc[1][3] += xv.y * wv.w;
            acc[2][0] += xv.z * wv.x; acc[2][1] += xv.z * wv.y;
            acc[2][2] += xv.z * wv.z; acc[2][3] += xv.z * wv.w;
            acc[3][0] += xv.w * wv.x; acc[3][1] += xv.w * wv.y;
            acc[3][2] += xv.w * wv.z; acc[3][3] += xv.w * wv.w;
        }
        __syncthreads();
    }
    float4 av = *(const float4*)&asrc[cg * 4];
    float4 dv = *(const float4*)&adst[cg * 4];
    int head = cg >> 3;
    bool leader = ((cg & 7) == 0);
    #pragma unroll
    for (int r = 0; r < 4; r++){
        int gr = r0 + rg * 4 + r;
        float4 o = make_float4(acc[r][0], acc[r][1], acc[r][2], acc[r][3]);
        if (gr < NND){
            ushort4 p;
            p.x = f2bf(o.x); p.y = f2bf(o.y); p.z = f2bf(o.z); p.w = f2bf(o.w);
            *(ushort4*)&h[gr * 128 + cg * 4] = p;
        }
        float sv = o.x * av.x + o.y * av.y + o.z * av.z + o.w * av.w;
        float sd = o.x * dv.x + o.y * dv.y + o.z * dv.z + o.w * dv.w;
        sv += __shfl_down(sv, 4, 64); sd += __shfl_down(sd, 4, 64);
        sv += __shfl_down(sv, 2, 64); sd += __shfl_down(sd, 2, 64);
        sv += __shfl_down(sv, 1, 64); sd += __shfl_down(sd, 1, 64);
        if (leader && gr < NND){
            als[gr * 4 + head] = sv;
            ald[gr * 4 + head] = sd;
        }
    }
}

// ------- CSR build: histogram of dst (real edges) + position assignment --------
// pose[e] write is coalesced; the atomic return-wait pipelines across waves.
__global__ void k_hist(const int* __restrict__ ei, int* __restrict__ cnt,
                       int* __restrict__ pose){
    int e = blockIdx.x * 256 + threadIdx.x;
    if (e >= NE) return;
    int d = ei[NE + e];
    pose[e] = atomicAdd(&cnt[d], 1);
}

// ---------------- scan phase 1: per-block sums of (cnt+1) -----------------------
__global__ __launch_bounds__(256) void k_scan1(const int* __restrict__ cnt,
                                               int* __restrict__ bsum){
    __shared__ int red[256];
    int t = threadIdx.x;
    int idx = blockIdx.x * 256 + t;
    red[t] = (idx < NND) ? (cnt[idx] + 1) : 0;   // +1 = self-loop slot
    __syncthreads();
    for (int off = 128; off > 0; off >>= 1){
        if (t < off) red[t] += red[t + off];
        __syncthreads();
    }
    if (t == 0) bsum[blockIdx.x] = red[0];
}

// ---------------- scan phase 2: scan the 196 block sums -------------------------
__global__ __launch_bounds__(256) void k_scan2(const int* __restrict__ bsum,
                                               int* __restrict__ boff,
                                               int* __restrict__ rs){
    __shared__ int ls[256];
    int t = threadIdx.x;
    int v = (t < SCB) ? bsum[t] : 0;
    ls[t] = v;
    __syncthreads();
    for (int off = 1; off < 256; off <<= 1){
        int u = (t >= off) ? ls[t - off] : 0;
        __syncthreads();
        ls[t] += u;
        __syncthreads();
    }
    if (t < SCB) boff[t] = ls[t] - bsum[t];
    if (t == 0)  rs[NND] = ls[255];              // total = NET
}

// ---------------- scan phase 3: per-block exclusive scan + offset ---------------
__global__ __launch_bounds__(256) void k_scan3(const int* __restrict__ cnt,
                                               const int* __restrict__ boff,
                                               int* __restrict__ rs){
    __shared__ int ls[256];
    int t = threadIdx.x;
    int idx = blockIdx.x * 256 + t;
    int v = (idx < NND) ? (cnt[idx] + 1) : 0;    // +1 = self-loop slot
    ls[t] = v;
    __syncthreads();
    for (int off = 1; off < 256; off <<= 1){
        int u = (t >= off) ? ls[t - off] : 0;
        __syncthreads();
        ls[t] += u;
        __syncthreads();
    }
    if (idx < NND) rs[idx] = boff[blockIdx.x] + ls[t] - v;
}

// ---------------- CSR build: scatter — NO atomics (pose precomputed) ------------
__global__ void k_scatter(const int* __restrict__ ei, const int* __restrict__ rs,
                          const int* __restrict__ pose, int* __restrict__ srcarr,
                          int* __restrict__ slotof){
    int e = blockIdx.x * 256 + threadIdx.x;
    if (e >= NET) return;
    if (e < NE){
        int s = ei[e], d = ei[NE + e];
        int slot = rs[d] + 1 + pose[e];          // slots 1..deg (0 = self-loop)
        srcarr[slot] = s;
        slotof[e] = slot;
    } else {
        int n = e - NE;
        srcarr[rs[n]] = n;
    }
}

// ---------------- per-edge attention weights -> CSR slot order ------------------
__global__ __launch_bounds__(256) void k_weight(
        const int* __restrict__ ei, const float* __restrict__ ef,
        const float4* __restrict__ als4, const float4* __restrict__ ald4,
        const float* __restrict__ Mg, const float* __restrict__ sc4g,
        const int* __restrict__ rs, const int* __restrict__ slotof,
        float4* __restrict__ wS){
    __shared__ float Ms[32];
    __shared__ float Scs[4];
    int t = threadIdx.x;
    if (t < 32) Ms[t] = Mg[t];
    if (t < 4)  Scs[t] = sc4g[t];
    __syncthreads();
    int e = blockIdx.x * 256 + t;
    if (e < NE){
        int s = ei[e], d = ei[NE + e];
        const float4* efp = (const float4*)ef;
        float4 u = efp[e * 2], v = efp[e * 2 + 1];
        float4 A = als4[s], D = ald4[d];
        float4 w;
        float* wp = &w.x;
        const float* Ap = &A.x; const float* Dp = &D.x;
        #pragma unroll
        for (int h = 0; h < 4; h++){
            float ae = u.x * Ms[0 + h]  + u.y * Ms[4 + h]
                     + u.z * Ms[8 + h]  + u.w * Ms[12 + h]
                     + v.x * Ms[16 + h] + v.y * Ms[20 + h]
                     + v.z * Ms[24 + h] + v.w * Ms[28 + h];
            float a = Ap[h] + Dp[h] + ae;
            a = a > 0.f ? a : 0.2f * a;
            wp[h] = __expf(a);
        }
        wS[slotof[e]] = w;
    } else if (e < NE + NND){
        int n = e - NE;
        float4 A = als4[n], D = ald4[n];
        float4 w;
        float* wp = &w.x;
        const float* Ap = &A.x; const float* Dp = &D.x;
        #pragma unroll
        for (int h = 0; h < 4; h++){
            float a = Ap[h] + Dp[h] + Scs[h];
            a = a > 0.f ? a : 0.2f * a;
            wp[h] = __expf(a);
        }
        wS[rs[n]] = w;
    }
}

// ---------------- gather: bf16 h rows, one wave/node, 8-deep pipeline -----------
__global__ __launch_bounds__(256) void k_gather(
        const int* __restrict__ srcarr, const int* __restrict__ rs,
        const float* __restrict__ wS,
        const unsigned int* __restrict__ HU,    // bf16x2 rows [NND][64]
        const float* __restrict__ b, float* __restrict__ out){
    int wid  = threadIdx.x >> 6;
    int lane = threadIdx.x & 63;
    int n = blockIdx.x * 4 + wid;
    int start = rs[n], end = rs[n + 1];
    int cnt = end - start;
    int mh = lane >> 4;
    float ax = 0.f, ay = 0.f, accw = 0.f;

    int s[8]; float w[8];
    int k = 0;
    if (cnt >= 8){
        #pragma unroll
        for (int j = 0; j < 8; j++){
            int i = start + j;
            s[j] = srcarr[i];
            w[j] = wS[i * 4 + mh];
        }
    }
    while (k + 8 <= cnt){
        int cs[8]; float cw[8];
        #pragma unroll
        for (int j = 0; j < 8; j++){ cs[j] = s[j]; cw[j] = w[j]; }
        k += 8;
        if (k + 8 <= cnt){
            #pragma unroll
            for (int j = 0; j < 8; j++){
                int i = start + k + j;
                s[j] = srcarr[i];
                w[j] = wS[i * 4 + mh];
            }
        }
        unsigned int hv[8];
        #pragma unroll
        for (int j = 0; j < 8; j++) hv[j] = HU[cs[j] * 64 + lane];
        #pragma unroll
        for (int j = 0; j < 8; j++){
            float lo = __uint_as_float(hv[j] << 16);
            float hi = __uint_as_float(hv[j] & 0xFFFF0000u);
            ax += cw[j] * lo;
            ay += cw[j] * hi;
            accw += cw[j];
        }
    }
    int rem = cnt - k;
    if (rem > 0){
        int ts[8]; float tw[8];
        #pragma unroll
        for (int j = 0; j < 8; j++){
            bool v = j < rem;
            int i = v ? (start + k + j) : start;
            ts[j] = srcarr[i];
            tw[j] = v ? wS[i * 4 + mh] : 0.f;
        }
        unsigned int hv[8];
        #pragma unroll
        for (int j = 0; j < 8; j++) hv[j] = HU[ts[j] * 64 + lane];
        #pragma unroll
        for (int j = 0; j < 8; j++){
            float lo = __uint_as_float(hv[j] << 16);
            float hi = __uint_as_float(hv[j] & 0xFFFF0000u);
            ax += tw[j] * lo;
            ay += tw[j] * hi;
            accw += tw[j];
        }
    }
    float inv = 1.f / (accw + 1e-16f);
    int c0 = 2 * lane;
    float2 o;
    o.x = frelu(ax * inv + b[c0]);
    o.y = frelu(ay * inv + b[c0 + 1]);
    ((float2*)out)[n * 64 + lane] = o;
}

// ---------------- global add pool: run-length compress sorted batch -------------
__global__ __launch_bounds__(128) void k_pool(const float* __restrict__ y,
                                              const int* __restrict__ batch,
                                              float* __restrict__ g){
    int c = threadIdx.x;
    int n0 = blockIdx.x * 32;
    if (n0 >= NND) return;
    int cur = batch[n0];
    float s = 0.f;
    for (int k = 0; k < 32; k++){
        int n = n0 + k;
        if (n >= NND) break;
        int bg = batch[n];
        if (bg != cur){
            atomicAdd(&g[cur * 128 + c], s);
            s = 0.f; cur = bg;
        }
        s += y[n * 128 + c];
    }
    atomicAdd(&g[cur * 128 + c], s);
}

// ---------------- MLP head: 128->32->32->1 --------------------------------------
__global__ void k_mlp(const float* __restrict__ g,
                      const float* __restrict__ lw1, const float* __restrict__ lb1,
                      const float* __restrict__ lw2, const float* __restrict__ lb2,
                      const float* __restrict__ lw3, const float* __restrict__ lb3,
                      float* __restrict__ out){
    __shared__ float t1[4][32];
    __shared__ float t2[4][32];
    int tid = threadIdx.x, sub = tid >> 5, j = tid & 31;
    int gi = blockIdx.x * 4 + sub;
    const float* gr = g + gi * 128;
    float s = lb1[j];
    for (int c = 0; c < 128; c++) s += gr[c] * lw1[c * 32 + j];
    t1[sub][j] = frelu(s);
    __syncthreads();
    float s2 = lb2[j];
    for (int k = 0; k < 32; k++) s2 += t1[sub][k] * lw2[k * 32 + j];
    t2[sub][j] = frelu(s2);
    __syncthreads();
    if (j == 0){
        float o = lb3[0];
        for (int k = 0; k < 32; k++) o += t2[sub][k] * lw3[k];
        out[gi] = frelu(o);
    }
}

extern "C" void kernel_launch(void* const* d_in, const int* in_sizes, int n_in,
                              void* d_out, int out_size, void* d_ws, size_t ws_size,
                              hipStream_t stream) {
    const float* x     = (const float*)d_in[0];
    const int*   ei    = (const int*)  d_in[1];
    const float* ef    = (const float*)d_in[2];
    const int*   batch = (const int*)  d_in[3];
    const float* W[3]   = {(const float*)d_in[4],  (const float*)d_in[10], (const float*)d_in[16]};
    const float* as_[3] = {(const float*)d_in[5],  (const float*)d_in[11], (const float*)d_in[17]};
    const float* ad_[3] = {(const float*)d_in[6],  (const float*)d_in[12], (const float*)d_in[18]};
    const float* We[3]  = {(const float*)d_in[7],  (const float*)d_in[13], (const float*)d_in[19]};
    const float* ae[3]  = {(const float*)d_in[8],  (const float*)d_in[14], (const float*)d_in[20]};
    const float* b_[3]  = {(const float*)d_in[9],  (const float*)d_in[15], (const float*)d_in[21]};
    const float* lw1 = (const float*)d_in[22]; const float* lb1 = (const float*)d_in[23];
    const float* lw2 = (const float*)d_in[24]; const float* lb2 = (const float*)d_in[25];
    const float* lw3 = (const float*)d_in[26]; const float* lb3 = (const float*)d_in[27];

    float* ws = (float*)d_ws;
    float* Bx   = ws;                      // layer in/out  [NND*128] fp32
    float* Hbf  = Bx + 6400000;            // h buffer bf16 [NND*128] (uses half)
    float* wSf  = Hbf + 6400000;           // weights/slot  [NET*4]
    float* als  = wSf + 3400000;           // [NND*4]
    float* ald  = als + 200000;            // [NND*4]
    float* g    = ald + 200000;            // [NG*128]
    float* acc8 = g + 262144;              // [8]
    float* M    = acc8 + 8;                // [96]
    float* sc   = M + 96;                  // [12] + pad
    int*   srcarr = (int*)(sc + 16);       // [NET]
    int*   slotof = srcarr + NET;          // [NE]
    int*   pose   = slotof + NE;           // [NE]
    int*   rs     = pose + NE;             // [NND+1] (+pad)
    int*   cnt    = rs + NND + 4;          // [NND]
    int*   bsum   = cnt + NND;             // [SCB]
    int*   boff   = bsum + SCB;            // [SCB]

    unsigned short* Hb = (unsigned short*)Hbf;

    hipMemsetAsync(acc8, 0, 8 * sizeof(float), stream);
    hipMemsetAsync(cnt,  0, NND * sizeof(int), stream);
    hipMemsetAsync(g,    0, NG * 128 * sizeof(float), stream);

    k_mean<<<256, 256, 0, stream>>>(ef, acc8);
    k_prep<<<1, 128, 0, stream>>>(acc8, We[0], ae[0], We[1], ae[1], We[2], ae[2], M, sc);

    k_hist<<<(NE + 255) / 256, 256, 0, stream>>>(ei, cnt, pose);
    k_scan1<<<SCB, 256, 0, stream>>>(cnt, bsum);
    k_scan2<<<1, 256, 0, stream>>>(bsum, boff, rs);
    k_scan3<<<SCB, 256, 0, stream>>>(cnt, boff, rs);
    k_scatter<<<(NET + 255) / 256, 256, 0, stream>>>(ei, rs, pose, srcarr, slotof);

    const float* xin = x;
    for (int l = 0; l < 3; l++){
        int Fin = (l == 0) ? 30 : 128;
        k_gemm<<<(NND + 31) / 32, 256, 0, stream>>>(xin, W[l], as_[l], ad_[l],
                                                    Hb, als, ald, Fin);
        k_weight<<<(NE + NND + 255) / 256, 256, 0, stream>>>(
            ei, ef, (const float4*)als, (const float4*)ald,
            M + l * 32, sc + l * 4, rs, slotof, (float4*)wSf);
        k_gather<<<NND / 4, 256, 0, stream>>>(srcarr, rs, wSf,
                                              (const unsigned int*)Hb, b_[l], Bx);
        xin = Bx;
    }

    k_pool<<<(NND + 31) / 32, 128, 0, stream>>>(Bx, batch, g);
    k_mlp<<<NG / 4, 128, 0, stream>>>(g, lw1, lb1, lw2, lb2, lw3, lb3, (float*)d_out);
}